// Round 3
// baseline (899.555 us; speedup 1.0000x reference)
//
#include <hip/hip_runtime.h>
#include <hip/hip_bf16.h>
#include <cstdint>
#include <cstddef>

// Problem constants
constexpr int B_  = 2;
constexpr int T_  = 2048;
constexpr int D_  = 2048;
constexpr int H_  = 8;
constexpr int HD_ = 128;
constexpr int C_  = 1024;   // H*HD
constexpr int BT_ = 64;
constexpr int NT_ = 32;     // T/BT
constexpr int M_  = 4096;   // B*T
constexpr float EPS_RMS = 1.1920929e-07f;

typedef __bf16 bf16x8 __attribute__((ext_vector_type(8)));
typedef float f32x4 __attribute__((ext_vector_type(4)));

typedef const __attribute__((address_space(1))) unsigned int* gptr_t;
typedef __attribute__((address_space(3))) unsigned int* lptr_t;

__device__ __forceinline__ void gload16(const void* g, void* l) {
  __builtin_amdgcn_global_load_lds((gptr_t)g, (lptr_t)l, 16, 0, 0);
}

// ---------------------------------------------------------------------------
// bf16 MFMA GEMM (m97 structure): C[M,N] = A[M,K] @ Bt[N,K]^T  (unchanged R2)
// ---------------------------------------------------------------------------
template <typename OutT>
__global__ __launch_bounds__(256) void gemm_bf16k(
    const __hip_bfloat16* __restrict__ A, const __hip_bfloat16* __restrict__ Bt,
    OutT* __restrict__ C, int N, int K) {
  __shared__ __hip_bfloat16 sA[128 * 32];
  __shared__ __hip_bfloat16 sB[128 * 32];
  const int tid = threadIdx.x;
  const int lane = tid & 63;
  const int m0 = blockIdx.y * 128, n0 = blockIdx.x * 128;
  const int wm = ((tid >> 6) >> 1) * 64, wn = ((tid >> 6) & 1) * 64;
  f32x4 acc[4][4];
#pragma unroll
  for (int i = 0; i < 4; ++i)
#pragma unroll
    for (int j = 0; j < 4; ++j) acc[i][j] = (f32x4)(0.f);
  const int f0 = tid, f1 = tid + 256;
  const int r0 = f0 >> 2, c0 = (f0 & 3) * 8;
  const int r1 = f1 >> 2, c1 = (f1 & 3) * 8;
  const size_t aoff0 = (size_t)(m0 + r0) * K + c0;
  const size_t aoff1 = (size_t)(m0 + r1) * K + c1;
  const size_t boff0 = (size_t)(n0 + r0) * K + c0;
  const size_t boff1 = (size_t)(n0 + r1) * K + c1;
  const int lr = lane & 15, lk = (lane >> 4) * 8;
  for (int k0 = 0; k0 < K; k0 += 32) {
    __syncthreads();
    gload16(A + aoff0 + k0, &sA[f0 * 8]);
    gload16(A + aoff1 + k0, &sA[f1 * 8]);
    gload16(Bt + boff0 + k0, &sB[f0 * 8]);
    gload16(Bt + boff1 + k0, &sB[f1 * 8]);
    __syncthreads();
    bf16x8 af[4], bfr[4];
#pragma unroll
    for (int i = 0; i < 4; ++i)
      af[i] = *(const bf16x8*)&sA[(wm + i * 16 + lr) * 32 + lk];
#pragma unroll
    for (int j = 0; j < 4; ++j)
      bfr[j] = *(const bf16x8*)&sB[(wn + j * 16 + lr) * 32 + lk];
#pragma unroll
    for (int i = 0; i < 4; ++i)
#pragma unroll
      for (int j = 0; j < 4; ++j)
        acc[i][j] = __builtin_amdgcn_mfma_f32_16x16x32_bf16(af[i], bfr[j], acc[i][j], 0, 0, 0);
  }
  const int er = (lane >> 4) * 4, ec = lane & 15;
#pragma unroll
  for (int i = 0; i < 4; ++i) {
#pragma unroll
    for (int j = 0; j < 4; ++j) {
      int row = m0 + wm + i * 16 + er;
      int col = n0 + wn + j * 16 + ec;
#pragma unroll
      for (int r = 0; r < 4; ++r) {
        float v = acc[i][j][r];
        if constexpr (sizeof(OutT) == 2)
          C[(size_t)(row + r) * N + col] = __float2bfloat16(v);
        else
          C[(size_t)(row + r) * N + col] = v;
      }
    }
  }
}

__global__ __launch_bounds__(256) void gemm_bf16_sk(
    const __hip_bfloat16* __restrict__ A, const __hip_bfloat16* __restrict__ Bt,
    float* __restrict__ Cp, int N, int K, int KS) {
  __shared__ __hip_bfloat16 sA[128 * 32];
  __shared__ __hip_bfloat16 sB[128 * 32];
  const int tid = threadIdx.x;
  const int lane = tid & 63;
  const int m0 = blockIdx.y * 128, n0 = blockIdx.x * 128;
  const int wm = ((tid >> 6) >> 1) * 64, wn = ((tid >> 6) & 1) * 64;
  const int kb = blockIdx.z * KS;
  float* Cs = Cp + (size_t)blockIdx.z * ((size_t)gridDim.y * 128) * N;
  f32x4 acc[4][4];
#pragma unroll
  for (int i = 0; i < 4; ++i)
#pragma unroll
    for (int j = 0; j < 4; ++j) acc[i][j] = (f32x4)(0.f);
  const int f0 = tid, f1 = tid + 256;
  const int r0 = f0 >> 2, c0 = (f0 & 3) * 8;
  const int r1 = f1 >> 2, c1 = (f1 & 3) * 8;
  const size_t aoff0 = (size_t)(m0 + r0) * K + c0;
  const size_t aoff1 = (size_t)(m0 + r1) * K + c1;
  const size_t boff0 = (size_t)(n0 + r0) * K + c0;
  const size_t boff1 = (size_t)(n0 + r1) * K + c1;
  const int lr = lane & 15, lk = (lane >> 4) * 8;
  for (int k0 = kb; k0 < kb + KS; k0 += 32) {
    __syncthreads();
    gload16(A + aoff0 + k0, &sA[f0 * 8]);
    gload16(A + aoff1 + k0, &sA[f1 * 8]);
    gload16(Bt + boff0 + k0, &sB[f0 * 8]);
    gload16(Bt + boff1 + k0, &sB[f1 * 8]);
    __syncthreads();
    bf16x8 af[4], bfr[4];
#pragma unroll
    for (int i = 0; i < 4; ++i)
      af[i] = *(const bf16x8*)&sA[(wm + i * 16 + lr) * 32 + lk];
#pragma unroll
    for (int j = 0; j < 4; ++j)
      bfr[j] = *(const bf16x8*)&sB[(wn + j * 16 + lr) * 32 + lk];
#pragma unroll
    for (int i = 0; i < 4; ++i)
#pragma unroll
      for (int j = 0; j < 4; ++j)
        acc[i][j] = __builtin_amdgcn_mfma_f32_16x16x32_bf16(af[i], bfr[j], acc[i][j], 0, 0, 0);
  }
  const int er = (lane >> 4) * 4, ec = lane & 15;
#pragma unroll
  for (int i = 0; i < 4; ++i)
#pragma unroll
    for (int j = 0; j < 4; ++j) {
      int row = m0 + wm + i * 16 + er;
      int col = n0 + wn + j * 16 + ec;
#pragma unroll
      for (int r = 0; r < 4; ++r)
        Cs[(size_t)(row + r) * N + col] = acc[i][j][r];
    }
}

__global__ __launch_bounds__(256) void reduce_dg(
    const float* __restrict__ slabs, __hip_bfloat16* __restrict__ adb,
    __hip_bfloat16* __restrict__ gdb) {
  int idx = blockIdx.x * 256 + threadIdx.x;
  int m = idx >> 8, c = idx & 255;
  const size_t ss = (size_t)M_ * 256;
  float s = slabs[idx] + slabs[idx + ss] + slabs[idx + 2 * ss] + slabs[idx + 3 * ss];
  if (c < 128) adb[(size_t)m * 128 + c] = __float2bfloat16(s);
  else         gdb[(size_t)m * 128 + (c - 128)] = __float2bfloat16(s);
}

__global__ __launch_bounds__(256) void cvt_bf(
    const float* __restrict__ in, __hip_bfloat16* __restrict__ out) {
  size_t i = ((size_t)blockIdx.x * 256 + threadIdx.x) * 4;
  float4 v = *(const float4*)(in + i);
  out[i + 0] = __float2bfloat16(v.x);
  out[i + 1] = __float2bfloat16(v.y);
  out[i + 2] = __float2bfloat16(v.z);
  out[i + 3] = __float2bfloat16(v.w);
}

__global__ __launch_bounds__(256) void tconv(
    const float* __restrict__ W, __hip_bfloat16* __restrict__ Wt, int K, int N) {
  __shared__ float tile[32][33];
  int tx = threadIdx.x & 31, ty = threadIdx.x >> 5;
  int kb = blockIdx.y * 32, nb = blockIdx.x * 32;
#pragma unroll
  for (int s = 0; s < 4; ++s) {
    int kk = ty + s * 8;
    tile[kk][tx] = W[(size_t)(kb + kk) * N + nb + tx];
  }
  __syncthreads();
#pragma unroll
  for (int s = 0; s < 4; ++s) {
    int nn = ty + s * 8;
    Wt[(size_t)(nb + nn) * K + kb + tx] = __float2bfloat16(tile[tx][nn]);
  }
}

// ---------------------------------------------------------------------------
// chunk_front: per (b,h,n) chunk — gate cumsum, k-conv+norm -> kp/km,
// v-conv+silu, Akk = km@kp^T (strict lower), dual triangular solve
// (kp->w, v->u, 256 independent columns), P = km^T @ u.
// Writes gc, km, w, u, P to global.   LDS ~149.5 KB -> 1 block/CU.
// ---------------------------------------------------------------------------
__global__ __launch_bounds__(256, 1) void chunk_front(
    const __hip_bfloat16* __restrict__ pre_qkv, const float* __restrict__ a_full,
    const float* __restrict__ ckw, const float* __restrict__ ckb,
    const float* __restrict__ cvw, const float* __restrict__ cvb,
    float* __restrict__ gc_g, float* __restrict__ km_g,
    float* __restrict__ w_g, float* __restrict__ u_g, float* __restrict__ P) {
  __shared__ float gcS[64][128];
  __shared__ float kpS[64][128];   // kp, then w (solve in place)
  __shared__ float kmS[64][128];
  __shared__ float vS[64][128];    // v, then u (solve in place)
  __shared__ __align__(16) char uniS[17408];  // raw bf16[67][128] | Akk f32[64][64]
  __shared__ float red[64][2];
  __hip_bfloat16* raw = (__hip_bfloat16*)uniS;
  float (*AkkS)[64] = (float(*)[64])uniS;

  const int tid = threadIdx.x;
  const int bhn = blockIdx.x;
  const int bh = bhn >> 5, n = bhn & 31;
  const int b = bh >> 3, h = bh & 7;
  const int t0 = n * 64;
  const int hoff = h * 128;

  // Phase A: gate cumsum
  for (int ci = tid; ci < 2048; ci += 256) {
    int r = ci >> 5, c4 = (ci & 31) * 4;
    *(float4*)&gcS[r][c4] =
        *(const float4*)(a_full + (size_t)(b * T_ + t0 + r) * C_ + hoff + c4);
  }
  __syncthreads();
  if (tid < 128) {
    float run = 0.f;
    for (int i = 0; i < 64; ++i) {
      float a = gcS[i][tid];
      float s = fmaxf(1.f / (1.f + __expf(-a)), 1e-6f);
      run += __logf(s);
      gcS[i][tid] = run;
    }
  }
  __syncthreads();
  const size_t gbase = ((size_t)bh * T_ + t0) * 128;
  for (int ci = tid; ci < 2048; ci += 256) {
    int r = ci >> 5, c4 = (ci & 31) * 4;
    *(float4*)(gc_g + gbase + r * 128 + c4) = *(const float4*)&gcS[r][c4];
  }

  const int d = tid & 127, r2 = tid >> 7;
  const int c = hoff + d;
  const int half = (tid >> 6) & 1;

  // Phase B: k conv + L2 norm + exp scaling
  for (int ci = tid; ci < 1072; ci += 256) {
    int rr = ci >> 4, c8 = (ci & 15) * 8;
    int gt = t0 - 3 + rr;
    uint4 val = make_uint4(0, 0, 0, 0);
    if (gt >= 0)
      val = *(const uint4*)(pre_qkv + (size_t)(b * T_ + gt) * (3 * C_) + C_ + hoff + c8);
    *(uint4*)&raw[rr * 128 + c8] = val;
  }
  __syncthreads();
  {
    const float w0 = ckw[c * 4 + 0], w1 = ckw[c * 4 + 1];
    const float w2 = ckw[c * 4 + 2], w3 = ckw[c * 4 + 3];
    const float bia = ckb[c];
    float cv[32];
#pragma unroll
    for (int i = 0; i < 32; ++i) {
      int r = 2 * i + r2;
      float acc = bia + w0 * __bfloat162float(raw[(r + 0) * 128 + d])
                      + w1 * __bfloat162float(raw[(r + 1) * 128 + d])
                      + w2 * __bfloat162float(raw[(r + 2) * 128 + d])
                      + w3 * __bfloat162float(raw[(r + 3) * 128 + d]);
      cv[i] = acc;
      float ss = acc * acc;
#pragma unroll
      for (int o = 1; o < 64; o <<= 1) ss += __shfl_xor(ss, o);
      if ((tid & 63) == 0) red[r][half] = ss;
    }
    __syncthreads();
#pragma unroll
    for (int i = 0; i < 32; ++i) {
      int r = 2 * i + r2;
      float inv = 1.f / fmaxf(sqrtf(red[r][0] + red[r][1]), 1e-12f);
      float g = gcS[r][d];
      float kn = cv[i] * inv;
      kpS[r][d] = kn * __expf(g);
      kmS[r][d] = kn * __expf(-g);
    }
  }
  __syncthreads();

  // Phase C: v conv + silu
  for (int ci = tid; ci < 1072; ci += 256) {
    int rr = ci >> 4, c8 = (ci & 15) * 8;
    int gt = t0 - 3 + rr;
    uint4 val = make_uint4(0, 0, 0, 0);
    if (gt >= 0)
      val = *(const uint4*)(pre_qkv + (size_t)(b * T_ + gt) * (3 * C_) + 2 * C_ + hoff + c8);
    *(uint4*)&raw[rr * 128 + c8] = val;
  }
  __syncthreads();
  {
    const float w0 = cvw[c * 4 + 0], w1 = cvw[c * 4 + 1];
    const float w2 = cvw[c * 4 + 2], w3 = cvw[c * 4 + 3];
    const float bia = cvb[c];
#pragma unroll
    for (int i = 0; i < 32; ++i) {
      int r = 2 * i + r2;
      float acc = bia + w0 * __bfloat162float(raw[(r + 0) * 128 + d])
                      + w1 * __bfloat162float(raw[(r + 1) * 128 + d])
                      + w2 * __bfloat162float(raw[(r + 2) * 128 + d])
                      + w3 * __bfloat162float(raw[(r + 3) * 128 + d]);
      vS[r][d] = acc * (1.f / (1.f + __expf(-acc)));
    }
  }
  __syncthreads();  // raw reads done -> AkkS may overwrite union

  // Phase D: Akk = km @ kp^T, strict lower
  {
    int i0 = (tid >> 4) * 4, j0 = (tid & 15) * 4;
    if (j0 <= i0 + 3) {
      float acc[4][4] = {{0.f}};
      int l5 = tid & 31;
#pragma unroll
      for (int s = 0; s < 32; ++s) {
        int dd = ((l5 + s) & 31) * 4;
        float4 xr[4], yr[4];
#pragma unroll
        for (int r = 0; r < 4; ++r) xr[r] = *(const float4*)&kmS[i0 + r][dd];
#pragma unroll
        for (int c2 = 0; c2 < 4; ++c2) yr[c2] = *(const float4*)&kpS[j0 + c2][dd];
#pragma unroll
        for (int r = 0; r < 4; ++r)
#pragma unroll
          for (int c2 = 0; c2 < 4; ++c2)
            acc[r][c2] += xr[r].x * yr[c2].x + xr[r].y * yr[c2].y +
                          xr[r].z * yr[c2].z + xr[r].w * yr[c2].w;
      }
#pragma unroll
      for (int r = 0; r < 4; ++r)
#pragma unroll
        for (int c2 = 0; c2 < 4; ++c2) {
          int i = i0 + r, j = j0 + c2;
          AkkS[i][j] = (j < i) ? acc[r][c2] : 0.f;
        }
    }
  }
  __syncthreads();

  // Phase E: forward substitution (unit lower). 256 independent columns.
  {
    int col = tid & 127;
    float (*Sm)[128] = (tid < 128) ? kpS : vS;
    for (int i = 1; i < 64; ++i) {
      float s = Sm[i][col];
      for (int j = 0; j < i; ++j) s -= AkkS[i][j] * Sm[j][col];
      Sm[i][col] = s;
    }
  }
  __syncthreads();

  // Phase F: global writes (w, u, km) + P = km^T @ u
  for (int ci = tid; ci < 2048; ci += 256) {
    int r = ci >> 5, c4 = (ci & 31) * 4;
    *(float4*)(w_g + gbase + r * 128 + c4) = *(const float4*)&kpS[r][c4];
    *(float4*)(u_g + gbase + r * 128 + c4) = *(const float4*)&vS[r][c4];
    *(float4*)(km_g + gbase + r * 128 + c4) = *(const float4*)&kmS[r][c4];
  }
  {
    int kd0 = (tid >> 4) * 8, vd0 = (tid & 15) * 8;
    float acc[8][8];
#pragma unroll
    for (int a = 0; a < 8; ++a)
#pragma unroll
      for (int b2 = 0; b2 < 8; ++b2) acc[a][b2] = 0.f;
    for (int i = 0; i < 64; ++i) {
      float kv[8], uv[8];
      *(float4*)(kv) = *(const float4*)&kmS[i][kd0];
      *(float4*)(kv + 4) = *(const float4*)&kmS[i][kd0 + 4];
      *(float4*)(uv) = *(const float4*)&vS[i][vd0];
      *(float4*)(uv + 4) = *(const float4*)&vS[i][vd0 + 4];
#pragma unroll
      for (int a = 0; a < 8; ++a)
#pragma unroll
        for (int b2 = 0; b2 < 8; ++b2) acc[a][b2] = fmaf(kv[a], uv[b2], acc[a][b2]);
    }
    float* dst = P + (size_t)bhn * 16384;
#pragma unroll
    for (int a = 0; a < 8; ++a) {
      *(float4*)(dst + (size_t)(kd0 + a) * 128 + vd0) =
          make_float4(acc[a][0], acc[a][1], acc[a][2], acc[a][3]);
      *(float4*)(dst + (size_t)(kd0 + a) * 128 + vd0 + 4) =
          make_float4(acc[a][4], acc[a][5], acc[a][6], acc[a][7]);
    }
  }
}

// ---------------------------------------------------------------------------
// scan over chunks (in place): P[n] -> state BEFORE chunk n; final -> Sout
// ---------------------------------------------------------------------------
__global__ __launch_bounds__(128) void scan_k(
    float* __restrict__ P, const float* __restrict__ gc, float* __restrict__ Sout) {
  int kd = blockIdx.x & 127;
  int bh = blockIdx.x >> 7;
  int vd = threadIdx.x;
  float s = 0.f;
  for (int n = 0; n < NT_; ++n) {
    size_t idx = (((size_t)bh * NT_ + n) * HD_ + kd) * HD_ + vd;
    float p = P[idx];
    P[idx] = s;
    float gl = gc[((size_t)bh * T_ + n * BT_ + (BT_ - 1)) * HD_ + kd];
    s = (s + p) * __expf(gl);
  }
  Sout[((size_t)bh * HD_ + kd) * HD_ + vd] = s;
}

// ---------------------------------------------------------------------------
// chunk_out: q-conv+norm -> qg, Aqk = qg@km^T (incl-diag lower),
// X = u - w@S, o = qg@S + Aqk@X, RMS-norm + gate -> o2 bf16 (B,T,C)
// ---------------------------------------------------------------------------
__global__ __launch_bounds__(256, 1) void chunk_out(
    const __hip_bfloat16* __restrict__ pre_qkv, const float* __restrict__ gc_g,
    const float* __restrict__ cqw, const float* __restrict__ cqb,
    const float* __restrict__ km_g, const float* __restrict__ w_g,
    const float* __restrict__ u_g, const float* __restrict__ Sst,
    const __hip_bfloat16* __restrict__ gatef, const float* __restrict__ normw,
    __hip_bfloat16* __restrict__ o2b) {
  __shared__ float qgS[64][128];
  __shared__ float kmS[64][128];
  __shared__ float wS[64][128];
  __shared__ float uS[64][128];    // u, then X in place
  __shared__ float spanel[16][128];
  __shared__ __align__(16) char uniS[17408];  // raw bf16[67][128] | Aq f32[64][64]
  __shared__ float red[64][2];
  __hip_bfloat16* raw = (__hip_bfloat16*)uniS;
  float (*AqS)[64] = (float(*)[64])uniS;

  const int tid = threadIdx.x;
  const int bhn = blockIdx.x;
  const int bh = bhn >> 5, n = bhn & 31;
  const int b = bh >> 3, h = bh & 7;
  const int t0 = n * 64;
  const int hoff = h * 128;
  const size_t gbase = ((size_t)bh * T_ + t0) * 128;

  // Phase 1: stage q raw + load km/w/u
  for (int ci = tid; ci < 1072; ci += 256) {
    int rr = ci >> 4, c8 = (ci & 15) * 8;
    int gt = t0 - 3 + rr;
    uint4 val = make_uint4(0, 0, 0, 0);
    if (gt >= 0)
      val = *(const uint4*)(pre_qkv + (size_t)(b * T_ + gt) * (3 * C_) + hoff + c8);
    *(uint4*)&raw[rr * 128 + c8] = val;
  }
  for (int ci = tid; ci < 2048; ci += 256) {
    int r = ci >> 5, c4 = (ci & 31) * 4;
    *(float4*)&kmS[r][c4] = *(const float4*)(km_g + gbase + r * 128 + c4);
    *(float4*)&wS[r][c4] = *(const float4*)(w_g + gbase + r * 128 + c4);
    *(float4*)&uS[r][c4] = *(const float4*)(u_g + gbase + r * 128 + c4);
  }
  __syncthreads();

  // Phase 2: q conv + L2 norm + e^gc
  const int d = tid & 127, r2 = tid >> 7;
  const int c = hoff + d;
  const int half = (tid >> 6) & 1;
  {
    const float w0 = cqw[c * 4 + 0], w1 = cqw[c * 4 + 1];
    const float w2 = cqw[c * 4 + 2], w3 = cqw[c * 4 + 3];
    const float bia = cqb[c];
    float cv[32];
#pragma unroll
    for (int i = 0; i < 32; ++i) {
      int r = 2 * i + r2;
      float acc = bia + w0 * __bfloat162float(raw[(r + 0) * 128 + d])
                      + w1 * __bfloat162float(raw[(r + 1) * 128 + d])
                      + w2 * __bfloat162float(raw[(r + 2) * 128 + d])
                      + w3 * __bfloat162float(raw[(r + 3) * 128 + d]);
      cv[i] = acc;
      float ss = acc * acc;
#pragma unroll
      for (int o = 1; o < 64; o <<= 1) ss += __shfl_xor(ss, o);
      if ((tid & 63) == 0) red[r][half] = ss;
    }
    __syncthreads();
#pragma unroll
    for (int i = 0; i < 32; ++i) {
      int r = 2 * i + r2;
      float inv = 1.f / fmaxf(sqrtf(red[r][0] + red[r][1]), 1e-12f);
      float g = gc_g[gbase + r * 128 + d];
      qgS[r][d] = cv[i] * inv * __expf(g);
    }
  }
  __syncthreads();  // raw dead -> AqS may use union

  // Phase 3: Aq = qg @ km^T, incl-diag lower
  {
    int i0 = (tid >> 4) * 4, j0 = (tid & 15) * 4;
    if (j0 <= i0 + 3) {
      float acc[4][4] = {{0.f}};
      int l5 = tid & 31;
#pragma unroll
      for (int s = 0; s < 32; ++s) {
        int dd = ((l5 + s) & 31) * 4;
        float4 xr[4], yr[4];
#pragma unroll
        for (int r = 0; r < 4; ++r) xr[r] = *(const float4*)&qgS[i0 + r][dd];
#pragma unroll
        for (int c2 = 0; c2 < 4; ++c2) yr[c2] = *(const float4*)&kmS[j0 + c2][dd];
#pragma unroll
        for (int r = 0; r < 4; ++r)
#pragma unroll
          for (int c2 = 0; c2 < 4; ++c2)
            acc[r][c2] += xr[r].x * yr[c2].x + xr[r].y * yr[c2].y +
                          xr[r].z * yr[c2].z + xr[r].w * yr[c2].w;
      }
#pragma unroll
      for (int r = 0; r < 4; ++r)
#pragma unroll
        for (int c2 = 0; c2 < 4; ++c2) {
          int i = i0 + r, j = j0 + c2;
          AqS[i][j] = (j <= i) ? acc[r][c2] : 0.f;
        }
    }
  }
  __syncthreads();

  // Phase 4: stream S panels; accX = w@S, accO = qg@S
  const int i0 = (tid >> 4) * 4, vd0 = (tid & 15) * 8;
  float accX[4][8], accO[4][8];
#pragma unroll
  for (int r = 0; r < 4; ++r)
#pragma unroll
    for (int e = 0; e < 8; ++e) { accX[r][e] = 0.f; accO[r][e] = 0.f; }
  const float* S = Sst + (size_t)bhn * 16384;
  for (int p = 0; p < 8; ++p) {
    __syncthreads();
    for (int ci = tid; ci < 512; ci += 256) {
      int r = ci >> 5, c4 = (ci & 31) * 4;
      *(float4*)&spanel[r][c4] = *(const float4*)(S + (size_t)(p * 16 + r) * 128 + c4);
    }
    __syncthreads();
#pragma unroll
    for (int q4 = 0; q4 < 4; ++q4) {
      int kd = q4 * 4;
      float4 wv[4], qv[4];
#pragma unroll
      for (int r = 0; r < 4; ++r) {
        wv[r] = *(const float4*)&wS[i0 + r][p * 16 + kd];
        qv[r] = *(const float4*)&qgS[i0 + r][p * 16 + kd];
      }
#pragma unroll
      for (int e = 0; e < 4; ++e) {
        float sv[8];
        *(float4*)(sv) = *(const float4*)&spanel[kd + e][vd0];
        *(float4*)(sv + 4) = *(const float4*)&spanel[kd + e][vd0 + 4];
#pragma unroll
        for (int r = 0; r < 4; ++r) {
          float we = (e == 0) ? wv[r].x : (e == 1) ? wv[r].y : (e == 2) ? wv[r].z : wv[r].w;
          float qe = (e == 0) ? qv[r].x : (e == 1) ? qv[r].y : (e == 2) ? qv[r].z : qv[r].w;
#pragma unroll
          for (int c2 = 0; c2 < 8; ++c2) {
            accX[r][c2] = fmaf(we, sv[c2], accX[r][c2]);
            accO[r][c2] = fmaf(qe, sv[c2], accO[r][c2]);
          }
        }
      }
    }
  }
  // X = u - accX (in place in uS)
  __syncthreads();
#pragma unroll
  for (int r = 0; r < 4; ++r) {
    float4 u0 = *(const float4*)&uS[i0 + r][vd0];
    float4 u1 = *(const float4*)&uS[i0 + r][vd0 + 4];
    *(float4*)&uS[i0 + r][vd0] =
        make_float4(u0.x - accX[r][0], u0.y - accX[r][1], u0.z - accX[r][2], u0.w - accX[r][3]);
    *(float4*)&uS[i0 + r][vd0 + 4] =
        make_float4(u1.x - accX[r][4], u1.y - accX[r][5], u1.z - accX[r][6], u1.w - accX[r][7]);
  }
  __syncthreads();

  // Phase 5: accO += Aq @ X (causal: j <= i)
  for (int j = 0; j <= i0 + 3; ++j) {
    float xv[8];
    *(float4*)(xv) = *(const float4*)&uS[j][vd0];
    *(float4*)(xv + 4) = *(const float4*)&uS[j][vd0 + 4];
#pragma unroll
    for (int r = 0; r < 4; ++r) {
      float a = (j <= i0 + r) ? AqS[i0 + r][j] : 0.f;
#pragma unroll
      for (int c2 = 0; c2 < 8; ++c2) accO[r][c2] = fmaf(a, xv[c2], accO[r][c2]);
    }
  }

  // Phase 6: RMS norm + gate + write bf16
  float4 nw0 = *(const float4*)(normw + vd0);
  float4 nw1 = *(const float4*)(normw + vd0 + 4);
  float nw[8] = {nw0.x, nw0.y, nw0.z, nw0.w, nw1.x, nw1.y, nw1.z, nw1.w};
#pragma unroll
  for (int r = 0; r < 4; ++r) {
    float ss = 0.f;
#pragma unroll
    for (int c2 = 0; c2 < 8; ++c2) ss += accO[r][c2] * accO[r][c2];
#pragma unroll
    for (int o = 1; o < 16; o <<= 1) ss += __shfl_xor(ss, o);
    float rms = rsqrtf(ss * (1.f / 128.f) + EPS_RMS);
    size_t orow = (size_t)(b * T_ + t0 + i0 + r) * C_ + hoff + vd0;
    uint4 gv4 = *(const uint4*)(gatef + orow);
    const __hip_bfloat16* gvp = (const __hip_bfloat16*)&gv4;
    __hip_bfloat16 outv[8];
#pragma unroll
    for (int c2 = 0; c2 < 8; ++c2) {
      float gv = __bfloat162float(gvp[c2]);
      float sig = 1.f / (1.f + __expf(-gv));
      outv[c2] = __float2bfloat16(accO[r][c2] * rms * nw[c2] * sig);
    }
    *(uint4*)(o2b + orow) = *(uint4*)outv;
  }
}

// ---------------------------------------------------------------------------
extern "C" void kernel_launch(void* const* d_in, const int* in_sizes, int n_in,
                              void* d_out, int out_size, void* d_ws, size_t ws_size,
                              hipStream_t stream) {
  (void)in_sizes; (void)n_in; (void)out_size;
  const float* x    = (const float*)d_in[0];
  const float* Wq   = (const float*)d_in[1];
  const float* Wk   = (const float*)d_in[2];
  const float* Wv   = (const float*)d_in[3];
  const float* cqw  = (const float*)d_in[4];
  const float* cqb  = (const float*)d_in[5];
  const float* ckw  = (const float*)d_in[6];
  const float* ckb  = (const float*)d_in[7];
  const float* cvw  = (const float*)d_in[8];
  const float* cvb  = (const float*)d_in[9];
  const float* Wad  = (const float*)d_in[10];
  const float* Wau  = (const float*)d_in[11];
  // d_in[12] = Wb : dead code in reference
  const float* Wgd  = (const float*)d_in[13];
  const float* Wgu  = (const float*)d_in[14];
  const float* normw= (const float*)d_in[15];
  const float* Wo   = (const float*)d_in[16];

  float* outp = (float*)d_out;
  float* Sout = outp + (size_t)M_ * D_;

  const size_t SZ = (size_t)M_ * C_;  // 4,194,304 f32 units

  float* ws = (float*)d_ws;
  __hip_bfloat16* pre_qkv = (__hip_bfloat16*)(ws);              // 1.5 SZ
  float* a_full = ws + 3 * SZ / 2;                               // 1 SZ
  __hip_bfloat16* gatef = (__hip_bfloat16*)(ws + 5 * SZ / 2);    // 0.5 SZ
  float* gc_g = ws + 3 * SZ;
  float* km_g = ws + 4 * SZ;
  float* w_g  = ws + 5 * SZ;
  float* u_g  = ws + 6 * SZ;
  float* Ppre = ws + 7 * SZ;                                     // 2 SZ
  __hip_bfloat16* xb = (__hip_bfloat16*)(ws + 9 * SZ);           // 1 SZ
  __hip_bfloat16* Wt_qkv = (__hip_bfloat16*)(ws + 10 * SZ);      // 0.75 SZ
  size_t off = 10 * SZ + 3 * SZ / 4;
  __hip_bfloat16* Wt_dg = (__hip_bfloat16*)(ws + off); off += 262144;
  __hip_bfloat16* Wt_au = (__hip_bfloat16*)(ws + off); off += 65536;
  __hip_bfloat16* Wt_gu = (__hip_bfloat16*)(ws + off); off += 65536;
  __hip_bfloat16* Wt_o  = (__hip_bfloat16*)(ws + off); off += 1048576;
  __hip_bfloat16* ad_bf = (__hip_bfloat16*)(ws + off); off += 262144;
  __hip_bfloat16* gd_bf = (__hip_bfloat16*)(ws + off); off += 262144;
  if (ws_size < off * sizeof(float)) return;

  float* slabs = Ppre;                         // dead before chunk_front writes P
  __hip_bfloat16* o2b = (__hip_bfloat16*)a_full;  // a_full dead after chunk_front

  // Phase 0: bf16 conversions
  cvt_bf<<<(int)((size_t)M_ * D_ / 1024), 256, 0, stream>>>(x, xb);
  tconv<<<dim3(C_ / 32, D_ / 32), 256, 0, stream>>>(Wq, Wt_qkv, D_, C_);
  tconv<<<dim3(C_ / 32, D_ / 32), 256, 0, stream>>>(Wk, Wt_qkv + (size_t)C_ * D_, D_, C_);
  tconv<<<dim3(C_ / 32, D_ / 32), 256, 0, stream>>>(Wv, Wt_qkv + 2 * (size_t)C_ * D_, D_, C_);
  tconv<<<dim3(HD_ / 32, D_ / 32), 256, 0, stream>>>(Wad, Wt_dg, D_, HD_);
  tconv<<<dim3(HD_ / 32, D_ / 32), 256, 0, stream>>>(Wgd, Wt_dg + (size_t)HD_ * D_, D_, HD_);
  tconv<<<dim3(C_ / 32, HD_ / 32), 256, 0, stream>>>(Wau, Wt_au, HD_, C_);
  tconv<<<dim3(C_ / 32, HD_ / 32), 256, 0, stream>>>(Wgu, Wt_gu, HD_, C_);
  tconv<<<dim3(D_ / 32, C_ / 32), 256, 0, stream>>>(Wo, Wt_o, C_, D_);

  // Phase 1: projections (MFMA bf16)
  gemm_bf16k<__hip_bfloat16><<<dim3(3 * C_ / 128, M_ / 128), 256, 0, stream>>>(
      xb, Wt_qkv, pre_qkv, 3 * C_, D_);
  gemm_bf16_sk<<<dim3(2, M_ / 128, 4), 256, 0, stream>>>(xb, Wt_dg, slabs, 256, D_, D_ / 4);
  reduce_dg<<<(int)((size_t)M_ * 256 / 256), 256, 0, stream>>>(slabs, ad_bf, gd_bf);
  gemm_bf16k<float><<<dim3(C_ / 128, M_ / 128), 256, 0, stream>>>(ad_bf, Wt_au, a_full, C_, HD_);
  gemm_bf16k<__hip_bfloat16><<<dim3(C_ / 128, M_ / 128), 256, 0, stream>>>(
      gd_bf, Wt_gu, gatef, C_, HD_);

  // Phase 2: fused chunk-local pipeline
  chunk_front<<<B_ * H_ * NT_, 256, 0, stream>>>(pre_qkv, a_full, ckw, ckb, cvw, cvb,
                                                 gc_g, km_g, w_g, u_g, Ppre);
  scan_k<<<B_ * H_ * HD_, 128, 0, stream>>>(Ppre, gc_g, Sout);
  chunk_out<<<B_ * H_ * NT_, 256, 0, stream>>>(pre_qkv, gc_g, cqw, cqb, km_g, w_g, u_g,
                                               Ppre, gatef, normw, o2b);

  // Phase 3: output projection
  gemm_bf16k<float><<<dim3(D_ / 128, M_ / 128), 256, 0, stream>>>(o2b, Wt_o, outp, D_, C_);
}

// Round 4
// 499.906 us; speedup vs baseline: 1.7994x; 1.7994x over previous
//
#include <hip/hip_runtime.h>
#include <hip/hip_bf16.h>
#include <cstdint>
#include <cstddef>

// Problem constants
constexpr int B_  = 2;
constexpr int T_  = 2048;
constexpr int D_  = 2048;
constexpr int H_  = 8;
constexpr int HD_ = 128;
constexpr int C_  = 1024;   // H*HD
constexpr int BT_ = 64;
constexpr int NT_ = 32;     // T/BT
constexpr int M_  = 4096;   // B*T
constexpr float EPS_RMS = 1.1920929e-07f;

typedef __bf16 bf16x8 __attribute__((ext_vector_type(8)));
typedef float f32x4 __attribute__((ext_vector_type(4)));

typedef const __attribute__((address_space(1))) unsigned int* gptr_t;
typedef __attribute__((address_space(3))) unsigned int* lptr_t;

__device__ __forceinline__ void gload16(const void* g, void* l) {
  __builtin_amdgcn_global_load_lds((gptr_t)g, (lptr_t)l, 16, 0, 0);
}

// ---------------------------------------------------------------------------
// bf16 MFMA GEMM (m97 structure): C[M,N] = A[M,K] @ Bt[N,K]^T  (unchanged R2)
// ---------------------------------------------------------------------------
template <typename OutT>
__global__ __launch_bounds__(256) void gemm_bf16k(
    const __hip_bfloat16* __restrict__ A, const __hip_bfloat16* __restrict__ Bt,
    OutT* __restrict__ C, int N, int K) {
  __shared__ __hip_bfloat16 sA[128 * 32];
  __shared__ __hip_bfloat16 sB[128 * 32];
  const int tid = threadIdx.x;
  const int lane = tid & 63;
  const int m0 = blockIdx.y * 128, n0 = blockIdx.x * 128;
  const int wm = ((tid >> 6) >> 1) * 64, wn = ((tid >> 6) & 1) * 64;
  f32x4 acc[4][4];
#pragma unroll
  for (int i = 0; i < 4; ++i)
#pragma unroll
    for (int j = 0; j < 4; ++j) acc[i][j] = (f32x4)(0.f);
  const int f0 = tid, f1 = tid + 256;
  const int r0 = f0 >> 2, c0 = (f0 & 3) * 8;
  const int r1 = f1 >> 2, c1 = (f1 & 3) * 8;
  const size_t aoff0 = (size_t)(m0 + r0) * K + c0;
  const size_t aoff1 = (size_t)(m0 + r1) * K + c1;
  const size_t boff0 = (size_t)(n0 + r0) * K + c0;
  const size_t boff1 = (size_t)(n0 + r1) * K + c1;
  const int lr = lane & 15, lk = (lane >> 4) * 8;
  for (int k0 = 0; k0 < K; k0 += 32) {
    __syncthreads();
    gload16(A + aoff0 + k0, &sA[f0 * 8]);
    gload16(A + aoff1 + k0, &sA[f1 * 8]);
    gload16(Bt + boff0 + k0, &sB[f0 * 8]);
    gload16(Bt + boff1 + k0, &sB[f1 * 8]);
    __syncthreads();
    bf16x8 af[4], bfr[4];
#pragma unroll
    for (int i = 0; i < 4; ++i)
      af[i] = *(const bf16x8*)&sA[(wm + i * 16 + lr) * 32 + lk];
#pragma unroll
    for (int j = 0; j < 4; ++j)
      bfr[j] = *(const bf16x8*)&sB[(wn + j * 16 + lr) * 32 + lk];
#pragma unroll
    for (int i = 0; i < 4; ++i)
#pragma unroll
      for (int j = 0; j < 4; ++j)
        acc[i][j] = __builtin_amdgcn_mfma_f32_16x16x32_bf16(af[i], bfr[j], acc[i][j], 0, 0, 0);
  }
  const int er = (lane >> 4) * 4, ec = lane & 15;
#pragma unroll
  for (int i = 0; i < 4; ++i) {
#pragma unroll
    for (int j = 0; j < 4; ++j) {
      int row = m0 + wm + i * 16 + er;
      int col = n0 + wn + j * 16 + ec;
#pragma unroll
      for (int r = 0; r < 4; ++r) {
        float v = acc[i][j][r];
        if constexpr (sizeof(OutT) == 2)
          C[(size_t)(row + r) * N + col] = __float2bfloat16(v);
        else
          C[(size_t)(row + r) * N + col] = v;
      }
    }
  }
}

__global__ __launch_bounds__(256) void gemm_bf16_sk(
    const __hip_bfloat16* __restrict__ A, const __hip_bfloat16* __restrict__ Bt,
    float* __restrict__ Cp, int N, int K, int KS) {
  __shared__ __hip_bfloat16 sA[128 * 32];
  __shared__ __hip_bfloat16 sB[128 * 32];
  const int tid = threadIdx.x;
  const int lane = tid & 63;
  const int m0 = blockIdx.y * 128, n0 = blockIdx.x * 128;
  const int wm = ((tid >> 6) >> 1) * 64, wn = ((tid >> 6) & 1) * 64;
  const int kb = blockIdx.z * KS;
  float* Cs = Cp + (size_t)blockIdx.z * ((size_t)gridDim.y * 128) * N;
  f32x4 acc[4][4];
#pragma unroll
  for (int i = 0; i < 4; ++i)
#pragma unroll
    for (int j = 0; j < 4; ++j) acc[i][j] = (f32x4)(0.f);
  const int f0 = tid, f1 = tid + 256;
  const int r0 = f0 >> 2, c0 = (f0 & 3) * 8;
  const int r1 = f1 >> 2, c1 = (f1 & 3) * 8;
  const size_t aoff0 = (size_t)(m0 + r0) * K + c0;
  const size_t aoff1 = (size_t)(m0 + r1) * K + c1;
  const size_t boff0 = (size_t)(n0 + r0) * K + c0;
  const size_t boff1 = (size_t)(n0 + r1) * K + c1;
  const int lr = lane & 15, lk = (lane >> 4) * 8;
  for (int k0 = kb; k0 < kb + KS; k0 += 32) {
    __syncthreads();
    gload16(A + aoff0 + k0, &sA[f0 * 8]);
    gload16(A + aoff1 + k0, &sA[f1 * 8]);
    gload16(Bt + boff0 + k0, &sB[f0 * 8]);
    gload16(Bt + boff1 + k0, &sB[f1 * 8]);
    __syncthreads();
    bf16x8 af[4], bfr[4];
#pragma unroll
    for (int i = 0; i < 4; ++i)
      af[i] = *(const bf16x8*)&sA[(wm + i * 16 + lr) * 32 + lk];
#pragma unroll
    for (int j = 0; j < 4; ++j)
      bfr[j] = *(const bf16x8*)&sB[(wn + j * 16 + lr) * 32 + lk];
#pragma unroll
    for (int i = 0; i < 4; ++i)
#pragma unroll
      for (int j = 0; j < 4; ++j)
        acc[i][j] = __builtin_amdgcn_mfma_f32_16x16x32_bf16(af[i], bfr[j], acc[i][j], 0, 0, 0);
  }
  const int er = (lane >> 4) * 4, ec = lane & 15;
#pragma unroll
  for (int i = 0; i < 4; ++i)
#pragma unroll
    for (int j = 0; j < 4; ++j) {
      int row = m0 + wm + i * 16 + er;
      int col = n0 + wn + j * 16 + ec;
#pragma unroll
      for (int r = 0; r < 4; ++r)
        Cs[(size_t)(row + r) * N + col] = acc[i][j][r];
    }
}

__global__ __launch_bounds__(256) void reduce_dg(
    const float* __restrict__ slabs, __hip_bfloat16* __restrict__ adb,
    __hip_bfloat16* __restrict__ gdb) {
  int idx = blockIdx.x * 256 + threadIdx.x;
  int m = idx >> 8, c = idx & 255;
  const size_t ss = (size_t)M_ * 256;
  float s = slabs[idx] + slabs[idx + ss] + slabs[idx + 2 * ss] + slabs[idx + 3 * ss];
  if (c < 128) adb[(size_t)m * 128 + c] = __float2bfloat16(s);
  else         gdb[(size_t)m * 128 + (c - 128)] = __float2bfloat16(s);
}

__global__ __launch_bounds__(256) void cvt_bf(
    const float* __restrict__ in, __hip_bfloat16* __restrict__ out) {
  size_t i = ((size_t)blockIdx.x * 256 + threadIdx.x) * 4;
  float4 v = *(const float4*)(in + i);
  out[i + 0] = __float2bfloat16(v.x);
  out[i + 1] = __float2bfloat16(v.y);
  out[i + 2] = __float2bfloat16(v.z);
  out[i + 3] = __float2bfloat16(v.w);
}

__global__ __launch_bounds__(256) void tconv(
    const float* __restrict__ W, __hip_bfloat16* __restrict__ Wt, int K, int N) {
  __shared__ float tile[32][33];
  int tx = threadIdx.x & 31, ty = threadIdx.x >> 5;
  int kb = blockIdx.y * 32, nb = blockIdx.x * 32;
#pragma unroll
  for (int s = 0; s < 4; ++s) {
    int kk = ty + s * 8;
    tile[kk][tx] = W[(size_t)(kb + kk) * N + nb + tx];
  }
  __syncthreads();
#pragma unroll
  for (int s = 0; s < 4; ++s) {
    int nn = ty + s * 8;
    Wt[(size_t)(nb + nn) * K + kb + tx] = __float2bfloat16(tile[tx][nn]);
  }
}

// ---------------------------------------------------------------------------
// gc: per (b,h,n) chunk, LDS-staged cumsum of log(clip(sigmoid(a))).
// grid = 512, 256 threads.
// ---------------------------------------------------------------------------
__global__ __launch_bounds__(256) void gc_lds(
    const float* __restrict__ a_full, float* __restrict__ gc) {
  __shared__ float gcS[64][128];
  const int tid = threadIdx.x;
  const int bhn = blockIdx.x;
  const int bh = bhn >> 5, n = bhn & 31;
  const int b = bh >> 3, h = bh & 7;
  const int t0 = n * 64, hoff = h * 128;
  for (int ci = tid; ci < 2048; ci += 256) {
    int r = ci >> 5, c4 = (ci & 31) * 4;
    *(float4*)&gcS[r][c4] =
        *(const float4*)(a_full + (size_t)(b * T_ + t0 + r) * C_ + hoff + c4);
  }
  __syncthreads();
  if (tid < 128) {
    float run = 0.f;
    for (int i = 0; i < 64; ++i) {
      float a = gcS[i][tid];
      float s = fmaxf(1.f / (1.f + __expf(-a)), 1e-6f);
      run += __logf(s);
      gcS[i][tid] = run;
    }
  }
  __syncthreads();
  const size_t gbase = ((size_t)bh * T_ + t0) * 128;
  for (int ci = tid; ci < 2048; ci += 256) {
    int r = ci >> 5, c4 = (ci & 31) * 4;
    *(float4*)(gc + gbase + r * 128 + c4) = *(const float4*)&gcS[r][c4];
  }
}

// ---------------------------------------------------------------------------
// Conv kernels (grid = B*T*H, 128 thr) with fused exp-scaling, bf16 outputs.
// ---------------------------------------------------------------------------
__global__ __launch_bounds__(128) void conv_q_bf(
    const __hip_bfloat16* __restrict__ pre, const float* __restrict__ gc,
    const float* __restrict__ cw, const float* __restrict__ cb,
    __hip_bfloat16* __restrict__ qg_bf) {
  int idx = blockIdx.x;
  int h = idx & 7;
  int t = (idx >> 3) & (T_ - 1);
  int b = idx >> 14;
  int d = threadIdx.x;
  int c = h * HD_ + d;
  const __hip_bfloat16* p = pre + (size_t)(b * T_ + t) * (3 * C_) + c;
  float w0 = cw[c * 4 + 0], w1 = cw[c * 4 + 1], w2 = cw[c * 4 + 2], w3 = cw[c * 4 + 3];
  float acc = cb[c] + w3 * __bfloat162float(p[0]);
  if (t > 0) acc += w2 * __bfloat162float(p[-(ptrdiff_t)(3 * C_)]);
  if (t > 1) acc += w1 * __bfloat162float(p[-2 * (ptrdiff_t)(3 * C_)]);
  if (t > 2) acc += w0 * __bfloat162float(p[-3 * (ptrdiff_t)(3 * C_)]);
  float ss = acc * acc;
#pragma unroll
  for (int o = 32; o > 0; o >>= 1) ss += __shfl_down(ss, o);
  __shared__ float red[2];
  if ((d & 63) == 0) red[d >> 6] = ss;
  __syncthreads();
  float nrm = fmaxf(sqrtf(red[0] + red[1]), 1e-12f);
  size_t oi = (((size_t)b * H_ + h) * T_ + t) * HD_ + d;
  float g = gc[oi];
  qg_bf[oi] = __float2bfloat16(acc / nrm * __expf(g));
}

__global__ __launch_bounds__(128) void conv_k_bf(
    const __hip_bfloat16* __restrict__ pre, const float* __restrict__ gc,
    const float* __restrict__ cw, const float* __restrict__ cb,
    __hip_bfloat16* __restrict__ kp_bf, __hip_bfloat16* __restrict__ km_bf) {
  int idx = blockIdx.x;
  int h = idx & 7;
  int t = (idx >> 3) & (T_ - 1);
  int b = idx >> 14;
  int d = threadIdx.x;
  int c = h * HD_ + d;
  const __hip_bfloat16* p = pre + (size_t)(b * T_ + t) * (3 * C_) + C_ + c;
  float w0 = cw[c * 4 + 0], w1 = cw[c * 4 + 1], w2 = cw[c * 4 + 2], w3 = cw[c * 4 + 3];
  float acc = cb[c] + w3 * __bfloat162float(p[0]);
  if (t > 0) acc += w2 * __bfloat162float(p[-(ptrdiff_t)(3 * C_)]);
  if (t > 1) acc += w1 * __bfloat162float(p[-2 * (ptrdiff_t)(3 * C_)]);
  if (t > 2) acc += w0 * __bfloat162float(p[-3 * (ptrdiff_t)(3 * C_)]);
  float ss = acc * acc;
#pragma unroll
  for (int o = 32; o > 0; o >>= 1) ss += __shfl_down(ss, o);
  __shared__ float red[2];
  if ((d & 63) == 0) red[d >> 6] = ss;
  __syncthreads();
  float nrm = fmaxf(sqrtf(red[0] + red[1]), 1e-12f);
  size_t oi = (((size_t)b * H_ + h) * T_ + t) * HD_ + d;
  float g = gc[oi];
  float kn = acc / nrm;
  kp_bf[oi] = __float2bfloat16(kn * __expf(g));
  km_bf[oi] = __float2bfloat16(kn * __expf(-g));
}

__global__ __launch_bounds__(128) void conv_v_bf(
    const __hip_bfloat16* __restrict__ pre, const float* __restrict__ cw,
    const float* __restrict__ cb, float* __restrict__ outp) {
  int idx = blockIdx.x;
  int h = idx & 7;
  int t = (idx >> 3) & (T_ - 1);
  int b = idx >> 14;
  int d = threadIdx.x;
  int c = h * HD_ + d;
  const __hip_bfloat16* p = pre + (size_t)(b * T_ + t) * (3 * C_) + 2 * C_ + c;
  float w0 = cw[c * 4 + 0], w1 = cw[c * 4 + 1], w2 = cw[c * 4 + 2], w3 = cw[c * 4 + 3];
  float acc = cb[c] + w3 * __bfloat162float(p[0]);
  if (t > 0) acc += w2 * __bfloat162float(p[-(ptrdiff_t)(3 * C_)]);
  if (t > 1) acc += w1 * __bfloat162float(p[-2 * (ptrdiff_t)(3 * C_)]);
  if (t > 2) acc += w0 * __bfloat162float(p[-3 * (ptrdiff_t)(3 * C_)]);
  float s = 1.f / (1.f + __expf(-acc));
  outp[(((size_t)b * H_ + h) * T_ + t) * HD_ + d] = acc * s;
}

// ---------------------------------------------------------------------------
// pairdot_mfma: per chunk, Akk = km@kp^T (f32, lower used) and
// Aq = qg@km^T (bf16, incl-diag lower, zero above).  No LDS; frags via L1.
// Waves 0,1 -> Akk rows 0-31/32-63; waves 2,3 -> Aq.
// ---------------------------------------------------------------------------
__global__ __launch_bounds__(256) void pairdot_mfma(
    const __hip_bfloat16* __restrict__ qg, const __hip_bfloat16* __restrict__ kp,
    const __hip_bfloat16* __restrict__ km, float* __restrict__ Akk,
    __hip_bfloat16* __restrict__ Aq) {
  const int tid = threadIdx.x;
  const int bhn = blockIdx.x;
  const int bh = bhn >> 5, n = bhn & 31;
  const size_t gbase = ((size_t)bh * T_ + (size_t)n * BT_) * HD_;
  const int wv = tid >> 6, lane = tid & 63;
  const int lr = lane & 15, lg = lane >> 4;
  const int prod = wv >> 1, rh = wv & 1;
  const __hip_bfloat16* A = (prod ? qg : km) + gbase;
  const __hip_bfloat16* Bt = (prod ? km : kp) + gbase;
  f32x4 acc[2][4];
#pragma unroll
  for (int i = 0; i < 2; ++i)
#pragma unroll
    for (int j = 0; j < 4; ++j) acc[i][j] = (f32x4)(0.f);
#pragma unroll
  for (int k0 = 0; k0 < 128; k0 += 32) {
    bf16x8 af[2], bfr[4];
#pragma unroll
    for (int i = 0; i < 2; ++i)
      af[i] = *(const bf16x8*)(A + (size_t)(rh * 32 + i * 16 + lr) * 128 + k0 + lg * 8);
#pragma unroll
    for (int j = 0; j < 4; ++j)
      bfr[j] = *(const bf16x8*)(Bt + (size_t)(j * 16 + lr) * 128 + k0 + lg * 8);
#pragma unroll
    for (int i = 0; i < 2; ++i)
#pragma unroll
      for (int j = 0; j < 4; ++j)
        acc[i][j] = __builtin_amdgcn_mfma_f32_16x16x32_bf16(af[i], bfr[j], acc[i][j], 0, 0, 0);
  }
  if (prod == 0) {
    float* dst = Akk + (size_t)bhn * 4096;
#pragma unroll
    for (int i = 0; i < 2; ++i)
#pragma unroll
      for (int j = 0; j < 4; ++j)
#pragma unroll
        for (int r = 0; r < 4; ++r) {
          int row = rh * 32 + i * 16 + lg * 4 + r;
          int col = j * 16 + lr;
          dst[row * 64 + col] = acc[i][j][r];  // upper junk: never read
        }
  } else {
    __hip_bfloat16* dst = Aq + (size_t)bhn * 4096;
#pragma unroll
    for (int i = 0; i < 2; ++i)
#pragma unroll
      for (int j = 0; j < 4; ++j)
#pragma unroll
        for (int r = 0; r < 4; ++r) {
          int row = rh * 32 + i * 16 + lg * 4 + r;
          int col = j * 16 + lr;
          float v = (col <= row) ? acc[i][j][r] : 0.f;
          dst[row * 64 + col] = __float2bfloat16(v);
        }
  }
}

// ---------------------------------------------------------------------------
// Unit-lower-triangular forward substitution; columns independent.
// half 0: rhs=kp_bf -> w_bf ; half 1: rhs=vv -> u (f32)
// ---------------------------------------------------------------------------
__global__ __launch_bounds__(128) void solvek2(
    const float* __restrict__ Akk, const __hip_bfloat16* __restrict__ kp_bf,
    const float* __restrict__ vv, __hip_bfloat16* __restrict__ w_bf,
    float* __restrict__ u) {
  __shared__ float A_s[BT_][BT_];
  __shared__ float sol[BT_][HD_];
  int bhn = blockIdx.x;
  int half = blockIdx.y;
  int tid = threadIdx.x;
  const float* Ab = Akk + (size_t)bhn * 4096;
#pragma unroll
  for (int s = 0; s < 32; ++s) {
    int e = tid + s * 128;
    ((float*)A_s)[e] = Ab[e];
  }
  const size_t base = ((size_t)(bhn >> 5) * T_ + (size_t)(bhn & 31) * BT_) * HD_;
  if (half) {
    for (int i = 0; i < BT_; ++i) sol[i][tid] = vv[base + (size_t)i * HD_ + tid];
  } else {
    for (int i = 0; i < BT_; ++i)
      sol[i][tid] = __bfloat162float(kp_bf[base + (size_t)i * HD_ + tid]);
  }
  __syncthreads();
  for (int i = 1; i < BT_; ++i) {
    float s = sol[i][tid];
    for (int j = 0; j < i; ++j) s -= A_s[i][j] * sol[j][tid];
    sol[i][tid] = s;
  }
  if (half) {
    for (int i = 0; i < BT_; ++i) u[base + (size_t)i * HD_ + tid] = sol[i][tid];
  } else {
    for (int i = 0; i < BT_; ++i)
      w_bf[base + (size_t)i * HD_ + tid] = __float2bfloat16(sol[i][tid]);
  }
}

// ---------------------------------------------------------------------------
// P[kd][vd] = sum_i km[i,kd]*u[i,vd] per chunk  (km bf16, u f32)
// ---------------------------------------------------------------------------
__global__ __launch_bounds__(256) void ppre_k2(
    const __hip_bfloat16* __restrict__ km_bf, const float* __restrict__ u,
    float* __restrict__ P) {
  __shared__ float Ks[BT_][HD_];
  __shared__ float Us[BT_][HD_];
  int bhn = blockIdx.x;
  const size_t base = ((size_t)(bhn >> 5) * T_ + (size_t)(bhn & 31) * BT_) * HD_;
  int tid = threadIdx.x;
  for (int ci = tid; ci < 1024; ci += 256) {
    int row = ci >> 4, c8 = (ci & 15) * 8;
    uint4 raw = *(const uint4*)(km_bf + base + (size_t)row * HD_ + c8);
    const __hip_bfloat16* hp = (const __hip_bfloat16*)&raw;
#pragma unroll
    for (int e = 0; e < 8; ++e) Ks[row][c8 + e] = __bfloat162float(hp[e]);
  }
  for (int ci = tid; ci < 2048; ci += 256) {
    int row = ci >> 5, c4 = (ci & 31) * 4;
    *(float4*)&Us[row][c4] = *(const float4*)(u + base + (size_t)row * HD_ + c4);
  }
  __syncthreads();
  int kd0 = (tid >> 4) * 8, vd0 = (tid & 15) * 8;
  float acc[8][8];
#pragma unroll
  for (int a = 0; a < 8; ++a)
#pragma unroll
    for (int b2 = 0; b2 < 8; ++b2) acc[a][b2] = 0.f;
  for (int i = 0; i < BT_; ++i) {
    float kv[8], uv[8];
    *(float4*)(kv) = *(const float4*)&Ks[i][kd0];
    *(float4*)(kv + 4) = *(const float4*)&Ks[i][kd0 + 4];
    *(float4*)(uv) = *(const float4*)&Us[i][vd0];
    *(float4*)(uv + 4) = *(const float4*)&Us[i][vd0 + 4];
#pragma unroll
    for (int a = 0; a < 8; ++a)
#pragma unroll
      for (int b2 = 0; b2 < 8; ++b2) acc[a][b2] = fmaf(kv[a], uv[b2], acc[a][b2]);
  }
  float* dst = P + (size_t)bhn * 16384;
#pragma unroll
  for (int a = 0; a < 8; ++a) {
    *(float4*)(dst + (size_t)(kd0 + a) * HD_ + vd0) =
        make_float4(acc[a][0], acc[a][1], acc[a][2], acc[a][3]);
    *(float4*)(dst + (size_t)(kd0 + a) * HD_ + vd0 + 4) =
        make_float4(acc[a][4], acc[a][5], acc[a][6], acc[a][7]);
  }
}

// ---------------------------------------------------------------------------
// scan over chunks (in place): P[n] -> state BEFORE chunk n; final -> Sout
// ---------------------------------------------------------------------------
__global__ __launch_bounds__(128) void scan_k(
    float* __restrict__ P, const float* __restrict__ gc, float* __restrict__ Sout) {
  int kd = blockIdx.x & 127;
  int bh = blockIdx.x >> 7;
  int vd = threadIdx.x;
  float s = 0.f;
  for (int n = 0; n < NT_; ++n) {
    size_t idx = (((size_t)bh * NT_ + n) * HD_ + kd) * HD_ + vd;
    float p = P[idx];
    P[idx] = s;
    float gl = gc[((size_t)bh * T_ + n * BT_ + (BT_ - 1)) * HD_ + kd];
    s = (s + p) * __expf(gl);
  }
  Sout[((size_t)bh * HD_ + kd) * HD_ + vd] = s;
}

// ---------------------------------------------------------------------------
// chunk_tail: per chunk — MFMA accX=w@S, accO=qg@S (S transposed bf16 in LDS),
// X=u-accX (transposed bf16 to LDS), MFMA accO+=Aq@X, fused RMS+gate epilogue.
// LDS ~54 KB -> 2 blocks/CU.  Wave tiling: 4 waves x (rows 0-63, cols 32*wv).
// ---------------------------------------------------------------------------
__global__ __launch_bounds__(256) void chunk_tail(
    const __hip_bfloat16* __restrict__ qg_bf, const __hip_bfloat16* __restrict__ w_bf,
    const float* __restrict__ u, const __hip_bfloat16* __restrict__ Aq_bf,
    const float* __restrict__ Sst, const __hip_bfloat16* __restrict__ gatef,
    const float* __restrict__ normw, __hip_bfloat16* __restrict__ o2b) {
  constexpr int STS = 136;  // ST row stride (pad: 128 would be conflict-free-less)
  constexpr int XTS = 72;   // XT row stride
  __shared__ __hip_bfloat16 ST[128 * STS];
  __shared__ __hip_bfloat16 XT[128 * XTS];
  __shared__ float red[64][4];
  const int tid = threadIdx.x;
  const int bhn = blockIdx.x;
  const int bh = bhn >> 5, n = bhn & 31;
  const int b = bh >> 3, h = bh & 7;
  const int t0 = n * 64, hoff = h * 128;
  const size_t gbase = ((size_t)bh * T_ + t0) * 128;
  const float* S = Sst + (size_t)bhn * 16384;

  // Phase A: stage S transposed to bf16 LDS
  for (int idx = tid; idx < 4096; idx += 256) {
    int kd = idx >> 5, c4 = (idx & 31) * 4;
    float4 v = *(const float4*)(S + (size_t)kd * 128 + c4);
    ST[(c4 + 0) * STS + kd] = __float2bfloat16(v.x);
    ST[(c4 + 1) * STS + kd] = __float2bfloat16(v.y);
    ST[(c4 + 2) * STS + kd] = __float2bfloat16(v.z);
    ST[(c4 + 3) * STS + kd] = __float2bfloat16(v.w);
  }
  __syncthreads();

  const int wv = tid >> 6, lane = tid & 63;
  const int lr = lane & 15, lg = lane >> 4;
  f32x4 accX[4][2], accO[4][2];
#pragma unroll
  for (int i = 0; i < 4; ++i)
#pragma unroll
    for (int j = 0; j < 2; ++j) { accX[i][j] = (f32x4)(0.f); accO[i][j] = (f32x4)(0.f); }

  // Phase B: accX = w @ S, accO = qg @ S
  const __hip_bfloat16* wrow = w_bf + gbase;
  const __hip_bfloat16* qrow = qg_bf + gbase;
#pragma unroll
  for (int k0 = 0; k0 < 128; k0 += 32) {
    bf16x8 aW[4], aQ[4], bS[2];
#pragma unroll
    for (int i = 0; i < 4; ++i) {
      aW[i] = *(const bf16x8*)(wrow + (size_t)(i * 16 + lr) * 128 + k0 + lg * 8);
      aQ[i] = *(const bf16x8*)(qrow + (size_t)(i * 16 + lr) * 128 + k0 + lg * 8);
    }
#pragma unroll
    for (int j = 0; j < 2; ++j)
      bS[j] = *(const bf16x8*)&ST[(wv * 32 + j * 16 + lr) * STS + k0 + lg * 8];
#pragma unroll
    for (int i = 0; i < 4; ++i)
#pragma unroll
      for (int j = 0; j < 2; ++j) {
        accX[i][j] = __builtin_amdgcn_mfma_f32_16x16x32_bf16(aW[i], bS[j], accX[i][j], 0, 0, 0);
        accO[i][j] = __builtin_amdgcn_mfma_f32_16x16x32_bf16(aQ[i], bS[j], accO[i][j], 0, 0, 0);
      }
  }

  // Phase C: X = u - accX, write transposed bf16 to XT
#pragma unroll
  for (int i = 0; i < 4; ++i)
#pragma unroll
    for (int j = 0; j < 2; ++j) {
      int row0 = i * 16 + lg * 4;
      int col = wv * 32 + j * 16 + lr;
      union { __hip_bfloat16 hx[4]; uint2 u2; } xv;
#pragma unroll
      for (int r = 0; r < 4; ++r) {
        float uu = u[gbase + (size_t)(row0 + r) * 128 + col];
        xv.hx[r] = __float2bfloat16(uu - accX[i][j][r]);
      }
      *(uint2*)&XT[col * XTS + row0] = xv.u2;
    }
  __syncthreads();

  // Phase D: accO += Aq @ X
  const __hip_bfloat16* aqb = Aq_bf + (size_t)bhn * 4096;
#pragma unroll
  for (int k0 = 0; k0 < 64; k0 += 32) {
    bf16x8 aA[4], bX[2];
#pragma unroll
    for (int i = 0; i < 4; ++i)
      aA[i] = *(const bf16x8*)(aqb + (size_t)(i * 16 + lr) * 64 + k0 + lg * 8);
#pragma unroll
    for (int j = 0; j < 2; ++j)
      bX[j] = *(const bf16x8*)&XT[(wv * 32 + j * 16 + lr) * XTS + k0 + lg * 8];
#pragma unroll
    for (int i = 0; i < 4; ++i)
#pragma unroll
      for (int j = 0; j < 2; ++j)
        accO[i][j] = __builtin_amdgcn_mfma_f32_16x16x32_bf16(aA[i], bX[j], accO[i][j], 0, 0, 0);
  }

  // Phase E: RMS + gate epilogue.  Cross-wave row reduction via red[][].
#pragma unroll
  for (int i = 0; i < 4; ++i)
#pragma unroll
    for (int r = 0; r < 4; ++r) {
      int row = i * 16 + lg * 4 + r;
      float o0 = accO[i][0][r], o1 = accO[i][1][r];
      float ss = o0 * o0 + o1 * o1;
#pragma unroll
      for (int o = 1; o < 16; o <<= 1) ss += __shfl_xor(ss, o);
      if (lr == 0) red[row][wv] = ss;
    }
  __syncthreads();
  float nw0 = normw[wv * 32 + lr];
  float nw1 = normw[wv * 32 + 16 + lr];
#pragma unroll
  for (int i = 0; i < 4; ++i)
#pragma unroll
    for (int r = 0; r < 4; ++r) {
      int row = i * 16 + lg * 4 + r;
      float tot = red[row][0] + red[row][1] + red[row][2] + red[row][3];
      float rms = rsqrtf(tot * (1.f / 128.f) + EPS_RMS);
      size_t orow = (size_t)(b * T_ + t0 + row) * C_ + hoff;
      int c0 = wv * 32 + lr, c1 = c0 + 16;
      float g0 = __bfloat162float(gatef[orow + c0]);
      float g1 = __bfloat162float(gatef[orow + c1]);
      float s0 = 1.f / (1.f + __expf(-g0));
      float s1 = 1.f / (1.f + __expf(-g1));
      o2b[orow + c0] = __float2bfloat16(accO[i][0][r] * rms * nw0 * s0);
      o2b[orow + c1] = __float2bfloat16(accO[i][1][r] * rms * nw1 * s1);
    }
}

// ---------------------------------------------------------------------------
extern "C" void kernel_launch(void* const* d_in, const int* in_sizes, int n_in,
                              void* d_out, int out_size, void* d_ws, size_t ws_size,
                              hipStream_t stream) {
  (void)in_sizes; (void)n_in; (void)out_size;
  const float* x    = (const float*)d_in[0];
  const float* Wq   = (const float*)d_in[1];
  const float* Wk   = (const float*)d_in[2];
  const float* Wv   = (const float*)d_in[3];
  const float* cqw  = (const float*)d_in[4];
  const float* cqb  = (const float*)d_in[5];
  const float* ckw  = (const float*)d_in[6];
  const float* ckb  = (const float*)d_in[7];
  const float* cvw  = (const float*)d_in[8];
  const float* cvb  = (const float*)d_in[9];
  const float* Wad  = (const float*)d_in[10];
  const float* Wau  = (const float*)d_in[11];
  // d_in[12] = Wb : dead code in reference
  const float* Wgd  = (const float*)d_in[13];
  const float* Wgu  = (const float*)d_in[14];
  const float* normw= (const float*)d_in[15];
  const float* Wo   = (const float*)d_in[16];

  float* outp = (float*)d_out;
  float* Sout = outp + (size_t)M_ * D_;

  const size_t SZ = (size_t)M_ * C_;  // 4,194,304 f32 units

  float* ws = (float*)d_ws;
  __hip_bfloat16* pre_qkv = (__hip_bfloat16*)(ws);                 // 1.5 SZ
  float* a_full = ws + 3 * SZ / 2;                                  // 1 SZ
  __hip_bfloat16* gatef = (__hip_bfloat16*)(ws + 5 * SZ / 2);       // 0.5 SZ
  float* gc_g = ws + 3 * SZ;                                        // 1 SZ
  float* vv   = ws + 4 * SZ;                                        // 1 SZ
  float* u_g  = ws + 5 * SZ;                                        // 1 SZ
  __hip_bfloat16* qg_bf = (__hip_bfloat16*)(ws + 6 * SZ);           // 0.5 SZ
  __hip_bfloat16* kp_bf = (__hip_bfloat16*)(ws + 13 * SZ / 2);      // 0.5 SZ
  __hip_bfloat16* km_bf = (__hip_bfloat16*)(ws + 7 * SZ);           // 0.5 SZ
  __hip_bfloat16* w_bf  = (__hip_bfloat16*)(ws + 15 * SZ / 2);      // 0.5 SZ
  float* Akk = ws + 8 * SZ;                                         // 0.5 SZ
  __hip_bfloat16* Aq_bf = (__hip_bfloat16*)(ws + 17 * SZ / 2);      // 0.25 SZ
  float* Ppre = ws + 35 * SZ / 4;                                   // 2 SZ
  __hip_bfloat16* xb = (__hip_bfloat16*)(ws + 43 * SZ / 4);         // 1 SZ
  __hip_bfloat16* Wt_qkv = (__hip_bfloat16*)(ws + 47 * SZ / 4);     // 0.75 SZ
  size_t off = 47 * SZ / 4 + 3 * SZ / 4;
  __hip_bfloat16* Wt_dg = (__hip_bfloat16*)(ws + off); off += 262144;
  __hip_bfloat16* Wt_au = (__hip_bfloat16*)(ws + off); off += 65536;
  __hip_bfloat16* Wt_gu = (__hip_bfloat16*)(ws + off); off += 65536;
  __hip_bfloat16* Wt_o  = (__hip_bfloat16*)(ws + off); off += 1048576;
  __hip_bfloat16* ad_bf = (__hip_bfloat16*)(ws + off); off += 262144;
  __hip_bfloat16* gd_bf = (__hip_bfloat16*)(ws + off); off += 262144;
  if (ws_size < off * sizeof(float)) return;

  float* slabs = Ppre;                            // dead before ppre_k2 writes P
  __hip_bfloat16* o2b = (__hip_bfloat16*)a_full;  // a_full dead after gc_lds

  // Phase 0: bf16 conversions
  cvt_bf<<<(int)((size_t)M_ * D_ / 1024), 256, 0, stream>>>(x, xb);
  tconv<<<dim3(C_ / 32, D_ / 32), 256, 0, stream>>>(Wq, Wt_qkv, D_, C_);
  tconv<<<dim3(C_ / 32, D_ / 32), 256, 0, stream>>>(Wk, Wt_qkv + (size_t)C_ * D_, D_, C_);
  tconv<<<dim3(C_ / 32, D_ / 32), 256, 0, stream>>>(Wv, Wt_qkv + 2 * (size_t)C_ * D_, D_, C_);
  tconv<<<dim3(HD_ / 32, D_ / 32), 256, 0, stream>>>(Wad, Wt_dg, D_, HD_);
  tconv<<<dim3(HD_ / 32, D_ / 32), 256, 0, stream>>>(Wgd, Wt_dg + (size_t)HD_ * D_, D_, HD_);
  tconv<<<dim3(C_ / 32, HD_ / 32), 256, 0, stream>>>(Wau, Wt_au, HD_, C_);
  tconv<<<dim3(C_ / 32, HD_ / 32), 256, 0, stream>>>(Wgu, Wt_gu, HD_, C_);
  tconv<<<dim3(D_ / 32, C_ / 32), 256, 0, stream>>>(Wo, Wt_o, C_, D_);

  // Phase 1: projections (MFMA bf16)
  gemm_bf16k<__hip_bfloat16><<<dim3(3 * C_ / 128, M_ / 128), 256, 0, stream>>>(
      xb, Wt_qkv, pre_qkv, 3 * C_, D_);
  gemm_bf16_sk<<<dim3(2, M_ / 128, 4), 256, 0, stream>>>(xb, Wt_dg, slabs, 256, D_, D_ / 4);
  reduce_dg<<<(int)((size_t)M_ * 256 / 256), 256, 0, stream>>>(slabs, ad_bf, gd_bf);
  gemm_bf16k<float><<<dim3(C_ / 128, M_ / 128), 256, 0, stream>>>(ad_bf, Wt_au, a_full, C_, HD_);
  gemm_bf16k<__hip_bfloat16><<<dim3(C_ / 128, M_ / 128), 256, 0, stream>>>(
      gd_bf, Wt_gu, gatef, C_, HD_);

  // Phase 2: gate cumsum, then convs with fused scaling
  gc_lds<<<B_ * H_ * NT_, 256, 0, stream>>>(a_full, gc_g);
  conv_q_bf<<<B_ * T_ * H_, 128, 0, stream>>>(pre_qkv, gc_g, cqw, cqb, qg_bf);
  conv_k_bf<<<B_ * T_ * H_, 128, 0, stream>>>(pre_qkv, gc_g, ckw, ckb, kp_bf, km_bf);
  conv_v_bf<<<B_ * T_ * H_, 128, 0, stream>>>(pre_qkv, cvw, cvb, vv);

  // Phase 3: chunk matrices + solve + state scan
  pairdot_mfma<<<B_ * H_ * NT_, 256, 0, stream>>>(qg_bf, kp_bf, km_bf, Akk, Aq_bf);
  solvek2<<<dim3(B_ * H_ * NT_, 2), 128, 0, stream>>>(Akk, kp_bf, vv, w_bf, u_g);
  ppre_k2<<<B_ * H_ * NT_, 256, 0, stream>>>(km_bf, u_g, Ppre);
  scan_k<<<B_ * H_ * HD_, 128, 0, stream>>>(Ppre, gc_g, Sout);

  // Phase 4: fused output tail + projection
  chunk_tail<<<B_ * H_ * NT_, 256, 0, stream>>>(qg_bf, w_bf, u_g, Aq_bf, Ppre,
                                                gatef, normw, o2b);
  gemm_bf16k<float><<<dim3(D_ / 128, M_ / 128), 256, 0, stream>>>(o2b, Wt_o, outp, D_, C_);
}

// Round 5
// 419.398 us; speedup vs baseline: 2.1449x; 1.1920x over previous
//
#include <hip/hip_runtime.h>
#include <hip/hip_bf16.h>
#include <cstdint>
#include <cstddef>

// Problem constants
constexpr int B_  = 2;
constexpr int T_  = 2048;
constexpr int D_  = 2048;
constexpr int H_  = 8;
constexpr int HD_ = 128;
constexpr int C_  = 1024;   // H*HD
constexpr int BT_ = 64;
constexpr int NT_ = 32;     // T/BT
constexpr int M_  = 4096;   // B*T
constexpr float EPS_RMS = 1.1920929e-07f;

typedef __bf16 bf16x8 __attribute__((ext_vector_type(8)));
typedef float f32x4 __attribute__((ext_vector_type(4)));

typedef const __attribute__((address_space(1))) unsigned int* gptr_t;
typedef __attribute__((address_space(3))) unsigned int* lptr_t;

__device__ __forceinline__ void gload16(const void* g, void* l) {
  __builtin_amdgcn_global_load_lds((gptr_t)g, (lptr_t)l, 16, 0, 0);
}

// ---------------------------------------------------------------------------
// bf16 MFMA GEMM (m97 structure): C[M,N] = A[M,K] @ Bt[N,K]^T  (unchanged)
// ---------------------------------------------------------------------------
template <typename OutT>
__global__ __launch_bounds__(256) void gemm_bf16k(
    const __hip_bfloat16* __restrict__ A, const __hip_bfloat16* __restrict__ Bt,
    OutT* __restrict__ C, int N, int K) {
  __shared__ __hip_bfloat16 sA[128 * 32];
  __shared__ __hip_bfloat16 sB[128 * 32];
  const int tid = threadIdx.x;
  const int lane = tid & 63;
  const int m0 = blockIdx.y * 128, n0 = blockIdx.x * 128;
  const int wm = ((tid >> 6) >> 1) * 64, wn = ((tid >> 6) & 1) * 64;
  f32x4 acc[4][4];
#pragma unroll
  for (int i = 0; i < 4; ++i)
#pragma unroll
    for (int j = 0; j < 4; ++j) acc[i][j] = (f32x4)(0.f);
  const int f0 = tid, f1 = tid + 256;
  const int r0 = f0 >> 2, c0 = (f0 & 3) * 8;
  const int r1 = f1 >> 2, c1 = (f1 & 3) * 8;
  const size_t aoff0 = (size_t)(m0 + r0) * K + c0;
  const size_t aoff1 = (size_t)(m0 + r1) * K + c1;
  const size_t boff0 = (size_t)(n0 + r0) * K + c0;
  const size_t boff1 = (size_t)(n0 + r1) * K + c1;
  const int lr = lane & 15, lk = (lane >> 4) * 8;
  for (int k0 = 0; k0 < K; k0 += 32) {
    __syncthreads();
    gload16(A + aoff0 + k0, &sA[f0 * 8]);
    gload16(A + aoff1 + k0, &sA[f1 * 8]);
    gload16(Bt + boff0 + k0, &sB[f0 * 8]);
    gload16(Bt + boff1 + k0, &sB[f1 * 8]);
    __syncthreads();
    bf16x8 af[4], bfr[4];
#pragma unroll
    for (int i = 0; i < 4; ++i)
      af[i] = *(const bf16x8*)&sA[(wm + i * 16 + lr) * 32 + lk];
#pragma unroll
    for (int j = 0; j < 4; ++j)
      bfr[j] = *(const bf16x8*)&sB[(wn + j * 16 + lr) * 32 + lk];
#pragma unroll
    for (int i = 0; i < 4; ++i)
#pragma unroll
      for (int j = 0; j < 4; ++j)
        acc[i][j] = __builtin_amdgcn_mfma_f32_16x16x32_bf16(af[i], bfr[j], acc[i][j], 0, 0, 0);
  }
  const int er = (lane >> 4) * 4, ec = lane & 15;
#pragma unroll
  for (int i = 0; i < 4; ++i) {
#pragma unroll
    for (int j = 0; j < 4; ++j) {
      int row = m0 + wm + i * 16 + er;
      int col = n0 + wn + j * 16 + ec;
#pragma unroll
      for (int r = 0; r < 4; ++r) {
        float v = acc[i][j][r];
        if constexpr (sizeof(OutT) == 2)
          C[(size_t)(row + r) * N + col] = __float2bfloat16(v);
        else
          C[(size_t)(row + r) * N + col] = v;
      }
    }
  }
}

__global__ __launch_bounds__(256) void gemm_bf16_sk(
    const __hip_bfloat16* __restrict__ A, const __hip_bfloat16* __restrict__ Bt,
    float* __restrict__ Cp, int N, int K, int KS) {
  __shared__ __hip_bfloat16 sA[128 * 32];
  __shared__ __hip_bfloat16 sB[128 * 32];
  const int tid = threadIdx.x;
  const int lane = tid & 63;
  const int m0 = blockIdx.y * 128, n0 = blockIdx.x * 128;
  const int wm = ((tid >> 6) >> 1) * 64, wn = ((tid >> 6) & 1) * 64;
  const int kb = blockIdx.z * KS;
  float* Cs = Cp + (size_t)blockIdx.z * ((size_t)gridDim.y * 128) * N;
  f32x4 acc[4][4];
#pragma unroll
  for (int i = 0; i < 4; ++i)
#pragma unroll
    for (int j = 0; j < 4; ++j) acc[i][j] = (f32x4)(0.f);
  const int f0 = tid, f1 = tid + 256;
  const int r0 = f0 >> 2, c0 = (f0 & 3) * 8;
  const int r1 = f1 >> 2, c1 = (f1 & 3) * 8;
  const size_t aoff0 = (size_t)(m0 + r0) * K + c0;
  const size_t aoff1 = (size_t)(m0 + r1) * K + c1;
  const size_t boff0 = (size_t)(n0 + r0) * K + c0;
  const size_t boff1 = (size_t)(n0 + r1) * K + c1;
  const int lr = lane & 15, lk = (lane >> 4) * 8;
  for (int k0 = kb; k0 < kb + KS; k0 += 32) {
    __syncthreads();
    gload16(A + aoff0 + k0, &sA[f0 * 8]);
    gload16(A + aoff1 + k0, &sA[f1 * 8]);
    gload16(Bt + boff0 + k0, &sB[f0 * 8]);
    gload16(Bt + boff1 + k0, &sB[f1 * 8]);
    __syncthreads();
    bf16x8 af[4], bfr[4];
#pragma unroll
    for (int i = 0; i < 4; ++i)
      af[i] = *(const bf16x8*)&sA[(wm + i * 16 + lr) * 32 + lk];
#pragma unroll
    for (int j = 0; j < 4; ++j)
      bfr[j] = *(const bf16x8*)&sB[(wn + j * 16 + lr) * 32 + lk];
#pragma unroll
    for (int i = 0; i < 4; ++i)
#pragma unroll
      for (int j = 0; j < 4; ++j)
        acc[i][j] = __builtin_amdgcn_mfma_f32_16x16x32_bf16(af[i], bfr[j], acc[i][j], 0, 0, 0);
  }
  const int er = (lane >> 4) * 4, ec = lane & 15;
#pragma unroll
  for (int i = 0; i < 4; ++i)
#pragma unroll
    for (int j = 0; j < 4; ++j) {
      int row = m0 + wm + i * 16 + er;
      int col = n0 + wn + j * 16 + ec;
#pragma unroll
      for (int r = 0; r < 4; ++r)
        Cs[(size_t)(row + r) * N + col] = acc[i][j][r];
    }
}

__global__ __launch_bounds__(256) void reduce_dg(
    const float* __restrict__ slabs, __hip_bfloat16* __restrict__ adb,
    __hip_bfloat16* __restrict__ gdb) {
  int idx = blockIdx.x * 256 + threadIdx.x;
  int m = idx >> 8, c = idx & 255;
  const size_t ss = (size_t)M_ * 256;
  float s = slabs[idx] + slabs[idx + ss] + slabs[idx + 2 * ss] + slabs[idx + 3 * ss];
  if (c < 128) adb[(size_t)m * 128 + c] = __float2bfloat16(s);
  else         gdb[(size_t)m * 128 + (c - 128)] = __float2bfloat16(s);
}

__global__ __launch_bounds__(256) void cvt_bf(
    const float* __restrict__ in, __hip_bfloat16* __restrict__ out) {
  size_t i = ((size_t)blockIdx.x * 256 + threadIdx.x) * 4;
  float4 v = *(const float4*)(in + i);
  out[i + 0] = __float2bfloat16(v.x);
  out[i + 1] = __float2bfloat16(v.y);
  out[i + 2] = __float2bfloat16(v.z);
  out[i + 3] = __float2bfloat16(v.w);
}

// Transpose-convert with z-multiplexing: up to 3 sources, contiguous dsts.
__global__ __launch_bounds__(256) void tconv_z(
    const float* __restrict__ W0, const float* __restrict__ W1,
    const float* __restrict__ W2, __hip_bfloat16* __restrict__ Wt, int K, int N) {
  const float* W = (blockIdx.z == 0) ? W0 : (blockIdx.z == 1) ? W1 : W2;
  __hip_bfloat16* dst = Wt + (size_t)blockIdx.z * K * N;
  __shared__ float tile[32][33];
  int tx = threadIdx.x & 31, ty = threadIdx.x >> 5;
  int kb = blockIdx.y * 32, nb = blockIdx.x * 32;
#pragma unroll
  for (int s = 0; s < 4; ++s) {
    int kk = ty + s * 8;
    tile[kk][tx] = W[(size_t)(kb + kk) * N + nb + tx];
  }
  __syncthreads();
#pragma unroll
  for (int s = 0; s < 4; ++s) {
    int nn = ty + s * 8;
    dst[(size_t)(nb + nn) * K + kb + tx] = __float2bfloat16(tile[tx][nn]);
  }
}

// ---------------------------------------------------------------------------
// gc: per (b,h,n) chunk, LDS-staged cumsum of log(clip(sigmoid(a))).
// ---------------------------------------------------------------------------
__global__ __launch_bounds__(256) void gc_lds(
    const float* __restrict__ a_full, float* __restrict__ gc) {
  __shared__ float gcS[64][128];
  const int tid = threadIdx.x;
  const int bhn = blockIdx.x;
  const int bh = bhn >> 5, n = bhn & 31;
  const int b = bh >> 3, h = bh & 7;
  const int t0 = n * 64, hoff = h * 128;
  for (int ci = tid; ci < 2048; ci += 256) {
    int r = ci >> 5, c4 = (ci & 31) * 4;
    *(float4*)&gcS[r][c4] =
        *(const float4*)(a_full + (size_t)(b * T_ + t0 + r) * C_ + hoff + c4);
  }
  __syncthreads();
  if (tid < 128) {
    float run = 0.f;
    for (int i = 0; i < 64; ++i) {
      float a = gcS[i][tid];
      float s = fmaxf(1.f / (1.f + __expf(-a)), 1e-6f);
      run += __logf(s);
      gcS[i][tid] = run;
    }
  }
  __syncthreads();
  const size_t gbase = ((size_t)bh * T_ + t0) * 128;
  for (int ci = tid; ci < 2048; ci += 256) {
    int r = ci >> 5, c4 = (ci & 31) * 4;
    *(float4*)(gc + gbase + r * 128 + c4) = *(const float4*)&gcS[r][c4];
  }
}

// ---------------------------------------------------------------------------
// Fused q/k/v conv (window 4) + norms/silu + exp scaling; bf16 head-layout out.
// grid = B*T*H (h fastest), 128 threads.
// ---------------------------------------------------------------------------
__global__ __launch_bounds__(128) void conv_qkv(
    const __hip_bfloat16* __restrict__ pre, const float* __restrict__ gc,
    const float* __restrict__ cqw, const float* __restrict__ cqb,
    const float* __restrict__ ckw, const float* __restrict__ ckb,
    const float* __restrict__ cvw, const float* __restrict__ cvb,
    __hip_bfloat16* __restrict__ qg, __hip_bfloat16* __restrict__ kp,
    __hip_bfloat16* __restrict__ km, __hip_bfloat16* __restrict__ vb) {
  int idx = blockIdx.x;
  int h = idx & 7;
  int t = (idx >> 3) & (T_ - 1);
  int b = idx >> 14;
  int d = threadIdx.x;
  int c = h * HD_ + d;
  const __hip_bfloat16* p = pre + (size_t)(b * T_ + t) * (3 * C_) + c;
  float aq, ak, av;
  {
    float w0 = cqw[c * 4], w1 = cqw[c * 4 + 1], w2 = cqw[c * 4 + 2], w3 = cqw[c * 4 + 3];
    aq = cqb[c] + w3 * __bfloat162float(p[0]);
    if (t > 0) aq += w2 * __bfloat162float(p[-(ptrdiff_t)(3 * C_)]);
    if (t > 1) aq += w1 * __bfloat162float(p[-2 * (ptrdiff_t)(3 * C_)]);
    if (t > 2) aq += w0 * __bfloat162float(p[-3 * (ptrdiff_t)(3 * C_)]);
  }
  {
    const __hip_bfloat16* pk = p + C_;
    float w0 = ckw[c * 4], w1 = ckw[c * 4 + 1], w2 = ckw[c * 4 + 2], w3 = ckw[c * 4 + 3];
    ak = ckb[c] + w3 * __bfloat162float(pk[0]);
    if (t > 0) ak += w2 * __bfloat162float(pk[-(ptrdiff_t)(3 * C_)]);
    if (t > 1) ak += w1 * __bfloat162float(pk[-2 * (ptrdiff_t)(3 * C_)]);
    if (t > 2) ak += w0 * __bfloat162float(pk[-3 * (ptrdiff_t)(3 * C_)]);
  }
  {
    const __hip_bfloat16* pv = p + 2 * C_;
    float w0 = cvw[c * 4], w1 = cvw[c * 4 + 1], w2 = cvw[c * 4 + 2], w3 = cvw[c * 4 + 3];
    av = cvb[c] + w3 * __bfloat162float(pv[0]);
    if (t > 0) av += w2 * __bfloat162float(pv[-(ptrdiff_t)(3 * C_)]);
    if (t > 1) av += w1 * __bfloat162float(pv[-2 * (ptrdiff_t)(3 * C_)]);
    if (t > 2) av += w0 * __bfloat162float(pv[-3 * (ptrdiff_t)(3 * C_)]);
  }
  float ssq = aq * aq, ssk = ak * ak;
#pragma unroll
  for (int o = 1; o < 64; o <<= 1) {
    ssq += __shfl_xor(ssq, o);
    ssk += __shfl_xor(ssk, o);
  }
  __shared__ float red[2][2];
  if ((d & 63) == 0) { red[0][d >> 6] = ssq; red[1][d >> 6] = ssk; }
  __syncthreads();
  float nq = fmaxf(sqrtf(red[0][0] + red[0][1]), 1e-12f);
  float nk = fmaxf(sqrtf(red[1][0] + red[1][1]), 1e-12f);
  size_t oi = (((size_t)b * H_ + h) * T_ + t) * HD_ + d;
  float g = gc[oi];
  float eg = __expf(g), emg = __expf(-g);
  qg[oi] = __float2bfloat16(aq / nq * eg);
  float kn = ak / nk;
  kp[oi] = __float2bfloat16(kn * eg);
  km[oi] = __float2bfloat16(kn * emg);
  vb[oi] = __float2bfloat16(av * (1.f / (1.f + __expf(-av))));
}

// ---------------------------------------------------------------------------
// chunk_mid: per chunk — MFMA pairdot (Akk -> LDS transposed, Aq -> global),
// register-resident dual forward substitution (w <- kp, u <- v),
// ppre PT[vd][kd] = sum_i u[i][vd]*km[i][kd].  LDS ~49.4 KB -> 2 blocks/CU.
// ---------------------------------------------------------------------------
__global__ __launch_bounds__(256) void chunk_mid(
    const __hip_bfloat16* __restrict__ qg, const __hip_bfloat16* __restrict__ kp,
    const __hip_bfloat16* __restrict__ km, const __hip_bfloat16* __restrict__ vb,
    __hip_bfloat16* __restrict__ Aq, __hip_bfloat16* __restrict__ w_bf,
    float* __restrict__ u_g, float* __restrict__ PT) {
  __shared__ float A_T[64][68];     // A_T[i][j] = Akk[j][i]
  __shared__ float solu[64][128];
  const int tid = threadIdx.x;
  const int bhn = blockIdx.x;
  const size_t gbase = ((size_t)(bhn >> 5) * T_ + (size_t)(bhn & 31) * BT_) * HD_;
  const int wv = tid >> 6, lane = tid & 63;
  const int lr = lane & 15, lg = lane >> 4;
  const int prod = wv >> 1, rh = wv & 1;

  // Phase 1: MFMA pair products.  waves 0,1 -> Akk (to LDS transposed);
  // waves 2,3 -> Aq (masked, to global bf16).
  {
    const __hip_bfloat16* A = (prod ? qg : km) + gbase;
    const __hip_bfloat16* Bt = (prod ? km : kp) + gbase;
    f32x4 acc[2][4];
#pragma unroll
    for (int i = 0; i < 2; ++i)
#pragma unroll
      for (int j = 0; j < 4; ++j) acc[i][j] = (f32x4)(0.f);
#pragma unroll
    for (int k0 = 0; k0 < 128; k0 += 32) {
      bf16x8 af[2], bfr[4];
#pragma unroll
      for (int i = 0; i < 2; ++i)
        af[i] = *(const bf16x8*)(A + (size_t)(rh * 32 + i * 16 + lr) * 128 + k0 + lg * 8);
#pragma unroll
      for (int j = 0; j < 4; ++j)
        bfr[j] = *(const bf16x8*)(Bt + (size_t)(j * 16 + lr) * 128 + k0 + lg * 8);
#pragma unroll
      for (int i = 0; i < 2; ++i)
#pragma unroll
        for (int j = 0; j < 4; ++j)
          acc[i][j] = __builtin_amdgcn_mfma_f32_16x16x32_bf16(af[i], bfr[j], acc[i][j], 0, 0, 0);
    }
    if (prod == 0) {
#pragma unroll
      for (int i = 0; i < 2; ++i)
#pragma unroll
        for (int j = 0; j < 4; ++j) {
          int row0 = rh * 32 + i * 16 + lg * 4;
          int col = j * 16 + lr;
          *(float4*)&A_T[col][row0] =
              make_float4(acc[i][j][0], acc[i][j][1], acc[i][j][2], acc[i][j][3]);
        }
    } else {
      __hip_bfloat16* dst = Aq + (size_t)bhn * 4096;
#pragma unroll
      for (int i = 0; i < 2; ++i)
#pragma unroll
        for (int j = 0; j < 4; ++j)
#pragma unroll
          for (int r = 0; r < 4; ++r) {
            int row = rh * 32 + i * 16 + lg * 4 + r;
            int col = j * 16 + lr;
            float v = (col <= row) ? acc[i][j][r] : 0.f;
            dst[row * 64 + col] = __float2bfloat16(v);
          }
    }
  }
  __syncthreads();

  // Phase 2: register-resident forward substitution (unit lower).
  // threads 0-127: w column (rhs kp); 128-255: u column (rhs v).
  {
    const int col = tid & 127;
    const __hip_bfloat16* rhs = ((tid < 128) ? kp : vb) + gbase;
    float s[64];
#pragma unroll
    for (int i = 0; i < 64; ++i)
      s[i] = __bfloat162float(rhs[(size_t)i * 128 + col]);
#pragma unroll
    for (int i = 0; i < 63; ++i) {
      const float si = s[i];
      const int j0 = (i + 1) & ~3;
#pragma unroll
      for (int j4 = j0; j4 < 64; j4 += 4) {
        float4 a4 = *(const float4*)&A_T[i][j4];
        if (j4 > i)     s[j4]     -= a4.x * si;
        if (j4 + 1 > i) s[j4 + 1] -= a4.y * si;
        if (j4 + 2 > i) s[j4 + 2] -= a4.z * si;
        if (j4 + 3 > i) s[j4 + 3] -= a4.w * si;
      }
    }
    if (tid < 128) {
#pragma unroll
      for (int i = 0; i < 64; ++i)
        w_bf[gbase + (size_t)i * 128 + col] = __float2bfloat16(s[i]);
    } else {
#pragma unroll
      for (int i = 0; i < 64; ++i) {
        u_g[gbase + (size_t)i * 128 + col] = s[i];
        solu[i][col] = s[i];
      }
    }
  }
  __syncthreads();

  // Phase 3: ppre — PT[vd][kd] = sum_i solu[i][vd] * km[i][kd]
  {
    const int kd0 = (tid >> 4) * 8, vd0 = (tid & 15) * 8;
    float acc[8][8];
#pragma unroll
    for (int a = 0; a < 8; ++a)
#pragma unroll
      for (int b2 = 0; b2 < 8; ++b2) acc[a][b2] = 0.f;
    for (int i = 0; i < 64; ++i) {
      uint4 raw = *(const uint4*)(km + gbase + (size_t)i * 128 + kd0);
      const __hip_bfloat16* hp = (const __hip_bfloat16*)&raw;
      float kv[8];
#pragma unroll
      for (int e = 0; e < 8; ++e) kv[e] = __bfloat162float(hp[e]);
      float uv[8];
      *(float4*)(uv)     = *(const float4*)&solu[i][vd0];
      *(float4*)(uv + 4) = *(const float4*)&solu[i][vd0 + 4];
#pragma unroll
      for (int a = 0; a < 8; ++a)
#pragma unroll
        for (int b2 = 0; b2 < 8; ++b2) acc[a][b2] = fmaf(kv[a], uv[b2], acc[a][b2]);
    }
    float* dst = PT + (size_t)bhn * 16384;
#pragma unroll
    for (int b2 = 0; b2 < 8; ++b2) {
      *(float4*)(dst + (size_t)(vd0 + b2) * 128 + kd0) =
          make_float4(acc[0][b2], acc[1][b2], acc[2][b2], acc[3][b2]);
      *(float4*)(dst + (size_t)(vd0 + b2) * 128 + kd0 + 4) =
          make_float4(acc[4][b2], acc[5][b2], acc[6][b2], acc[7][b2]);
    }
  }
}

// ---------------------------------------------------------------------------
// scan over chunks on PT layout: STg[n] = bf16(state BEFORE chunk n);
// final state scattered into Sout[bh][kd][vd] (f32, d_out).
// grid = B*H*128 (vd fastest), 128 threads (kd).
// ---------------------------------------------------------------------------
__global__ __launch_bounds__(128) void scan_pt(
    const float* __restrict__ PT, const float* __restrict__ gc,
    __hip_bfloat16* __restrict__ STg, float* __restrict__ Sout) {
  int vd = blockIdx.x & 127;
  int bh = blockIdx.x >> 7;
  int kd = threadIdx.x;
  float s = 0.f;
  for (int n = 0; n < NT_; ++n) {
    size_t idx = (((size_t)bh * NT_ + n) * HD_ + vd) * HD_ + kd;
    float p = PT[idx];
    STg[idx] = __float2bfloat16(s);
    float gl = gc[((size_t)bh * T_ + n * BT_ + (BT_ - 1)) * HD_ + kd];
    s = (s + p) * __expf(gl);
  }
  Sout[((size_t)bh * HD_ + kd) * HD_ + vd] = s;
}

// ---------------------------------------------------------------------------
// chunk_tail: per chunk — MFMA accX=w@S, accO=qg@S with S frags loaded
// DIRECTLY from global bf16 STg (already B-operand layout), X=u-accX
// (transposed bf16 to LDS), MFMA accO+=Aq@X, fused RMS+gate epilogue.
// ---------------------------------------------------------------------------
__global__ __launch_bounds__(256) void chunk_tail(
    const __hip_bfloat16* __restrict__ qg_bf, const __hip_bfloat16* __restrict__ w_bf,
    const float* __restrict__ u, const __hip_bfloat16* __restrict__ Aq_bf,
    const __hip_bfloat16* __restrict__ STg, const __hip_bfloat16* __restrict__ gatef,
    const float* __restrict__ normw, __hip_bfloat16* __restrict__ o2b) {
  constexpr int XTS = 72;   // XT row stride
  __shared__ __hip_bfloat16 XT[128 * XTS];
  __shared__ float red[64][4];
  const int tid = threadIdx.x;
  const int bhn = blockIdx.x;
  const int bh = bhn >> 5, n = bhn & 31;
  const int b = bh >> 3, h = bh & 7;
  const int t0 = n * 64, hoff = h * 128;
  const size_t gbase = ((size_t)bh * T_ + t0) * 128;
  const __hip_bfloat16* Sg = STg + (size_t)bhn * 16384;

  const int wv = tid >> 6, lane = tid & 63;
  const int lr = lane & 15, lg = lane >> 4;
  f32x4 accX[4][2], accO[4][2];
#pragma unroll
  for (int i = 0; i < 4; ++i)
#pragma unroll
    for (int j = 0; j < 2; ++j) { accX[i][j] = (f32x4)(0.f); accO[i][j] = (f32x4)(0.f); }

  // Phase B: accX = w @ S, accO = qg @ S  (S^T frags straight from global)
  const __hip_bfloat16* wrow = w_bf + gbase;
  const __hip_bfloat16* qrow = qg_bf + gbase;
#pragma unroll
  for (int k0 = 0; k0 < 128; k0 += 32) {
    bf16x8 aW[4], aQ[4], bS[2];
#pragma unroll
    for (int i = 0; i < 4; ++i) {
      aW[i] = *(const bf16x8*)(wrow + (size_t)(i * 16 + lr) * 128 + k0 + lg * 8);
      aQ[i] = *(const bf16x8*)(qrow + (size_t)(i * 16 + lr) * 128 + k0 + lg * 8);
    }
#pragma unroll
    for (int j = 0; j < 2; ++j)
      bS[j] = *(const bf16x8*)(Sg + (size_t)(wv * 32 + j * 16 + lr) * 128 + k0 + lg * 8);
#pragma unroll
    for (int i = 0; i < 4; ++i)
#pragma unroll
      for (int j = 0; j < 2; ++j) {
        accX[i][j] = __builtin_amdgcn_mfma_f32_16x16x32_bf16(aW[i], bS[j], accX[i][j], 0, 0, 0);
        accO[i][j] = __builtin_amdgcn_mfma_f32_16x16x32_bf16(aQ[i], bS[j], accO[i][j], 0, 0, 0);
      }
  }

  // Phase C: X = u - accX, write transposed bf16 to XT
#pragma unroll
  for (int i = 0; i < 4; ++i)
#pragma unroll
    for (int j = 0; j < 2; ++j) {
      int row0 = i * 16 + lg * 4;
      int col = wv * 32 + j * 16 + lr;
      union { __hip_bfloat16 hx[4]; uint2 u2; } xv;
#pragma unroll
      for (int r = 0; r < 4; ++r) {
        float uu = u[gbase + (size_t)(row0 + r) * 128 + col];
        xv.hx[r] = __float2bfloat16(uu - accX[i][j][r]);
      }
      *(uint2*)&XT[col * XTS + row0] = xv.u2;
    }
  __syncthreads();

  // Phase D: accO += Aq @ X
  const __hip_bfloat16* aqb = Aq_bf + (size_t)bhn * 4096;
#pragma unroll
  for (int k0 = 0; k0 < 64; k0 += 32) {
    bf16x8 aA[4], bX[2];
#pragma unroll
    for (int i = 0; i < 4; ++i)
      aA[i] = *(const bf16x8*)(aqb + (size_t)(i * 16 + lr) * 64 + k0 + lg * 8);
#pragma unroll
    for (int j = 0; j < 2; ++j)
      bX[j] = *(const bf16x8*)&XT[(wv * 32 + j * 16 + lr) * XTS + k0 + lg * 8];
#pragma unroll
    for (int i = 0; i < 4; ++i)
#pragma unroll
      for (int j = 0; j < 2; ++j)
        accO[i][j] = __builtin_amdgcn_mfma_f32_16x16x32_bf16(aA[i], bX[j], accO[i][j], 0, 0, 0);
  }

  // Phase E: RMS + gate epilogue.
#pragma unroll
  for (int i = 0; i < 4; ++i)
#pragma unroll
    for (int r = 0; r < 4; ++r) {
      int row = i * 16 + lg * 4 + r;
      float o0 = accO[i][0][r], o1 = accO[i][1][r];
      float ss = o0 * o0 + o1 * o1;
#pragma unroll
      for (int o = 1; o < 16; o <<= 1) ss += __shfl_xor(ss, o);
      if (lr == 0) red[row][wv] = ss;
    }
  __syncthreads();
  float nw0 = normw[wv * 32 + lr];
  float nw1 = normw[wv * 32 + 16 + lr];
#pragma unroll
  for (int i = 0; i < 4; ++i)
#pragma unroll
    for (int r = 0; r < 4; ++r) {
      int row = i * 16 + lg * 4 + r;
      float tot = red[row][0] + red[row][1] + red[row][2] + red[row][3];
      float rms = rsqrtf(tot * (1.f / 128.f) + EPS_RMS);
      size_t orow = (size_t)(b * T_ + t0 + row) * C_ + hoff;
      int c0 = wv * 32 + lr, c1 = c0 + 16;
      float g0 = __bfloat162float(gatef[orow + c0]);
      float g1 = __bfloat162float(gatef[orow + c1]);
      float s0 = 1.f / (1.f + __expf(-g0));
      float s1 = 1.f / (1.f + __expf(-g1));
      o2b[orow + c0] = __float2bfloat16(accO[i][0][r] * rms * nw0 * s0);
      o2b[orow + c1] = __float2bfloat16(accO[i][1][r] * rms * nw1 * s1);
    }
}

// ---------------------------------------------------------------------------
extern "C" void kernel_launch(void* const* d_in, const int* in_sizes, int n_in,
                              void* d_out, int out_size, void* d_ws, size_t ws_size,
                              hipStream_t stream) {
  (void)in_sizes; (void)n_in; (void)out_size;
  const float* x    = (const float*)d_in[0];
  const float* Wq   = (const float*)d_in[1];
  const float* Wk   = (const float*)d_in[2];
  const float* Wv   = (const float*)d_in[3];
  const float* cqw  = (const float*)d_in[4];
  const float* cqb  = (const float*)d_in[5];
  const float* ckw  = (const float*)d_in[6];
  const float* ckb  = (const float*)d_in[7];
  const float* cvw  = (const float*)d_in[8];
  const float* cvb  = (const float*)d_in[9];
  const float* Wad  = (const float*)d_in[10];
  const float* Wau  = (const float*)d_in[11];
  // d_in[12] = Wb : dead code in reference
  const float* Wgd  = (const float*)d_in[13];
  const float* Wgu  = (const float*)d_in[14];
  const float* normw= (const float*)d_in[15];
  const float* Wo   = (const float*)d_in[16];

  float* outp = (float*)d_out;
  float* Sout = outp + (size_t)M_ * D_;

  const size_t SZ = (size_t)M_ * C_;  // 4,194,304 f32 units

  float* ws = (float*)d_ws;
  __hip_bfloat16* pre_qkv = (__hip_bfloat16*)(ws);                 // 1.5 SZ
  float* a_full = ws + 3 * SZ / 2;                                  // 1 SZ
  __hip_bfloat16* gatef = (__hip_bfloat16*)(ws + 5 * SZ / 2);       // 0.5 SZ
  float* gc_g = ws + 3 * SZ;                                        // 1 SZ
  __hip_bfloat16* qg_bf = (__hip_bfloat16*)(ws + 4 * SZ);           // 0.5 SZ
  __hip_bfloat16* kp_bf = (__hip_bfloat16*)(ws + 9 * SZ / 2);       // 0.5 SZ
  __hip_bfloat16* km_bf = (__hip_bfloat16*)(ws + 5 * SZ);           // 0.5 SZ
  __hip_bfloat16* v_bf  = (__hip_bfloat16*)(ws + 11 * SZ / 2);      // 0.5 SZ
  __hip_bfloat16* w_bf  = (__hip_bfloat16*)(ws + 6 * SZ);           // 0.5 SZ
  float* u_g  = ws + 13 * SZ / 2;                                   // 1 SZ
  __hip_bfloat16* Aq_bf = (__hip_bfloat16*)(ws + 15 * SZ / 2);      // 0.25 SZ
  float* PT = ws + 31 * SZ / 4;                                     // 2 SZ
  __hip_bfloat16* STg = (__hip_bfloat16*)(ws + 39 * SZ / 4);        // 1 SZ (bf16)
  __hip_bfloat16* xb = (__hip_bfloat16*)(ws + 43 * SZ / 4);         // 1 SZ
  __hip_bfloat16* Wt_qkv = (__hip_bfloat16*)(ws + 47 * SZ / 4);     // 0.75 SZ
  size_t off = 47 * SZ / 4 + 3 * SZ / 4;
  __hip_bfloat16* Wt_dg = (__hip_bfloat16*)(ws + off); off += 262144;
  __hip_bfloat16* Wt_aug = (__hip_bfloat16*)(ws + off); off += 131072;  // Wau|Wgu
  __hip_bfloat16* Wt_o  = (__hip_bfloat16*)(ws + off); off += 1048576;
  __hip_bfloat16* ad_bf = (__hip_bfloat16*)(ws + off); off += 262144;
  __hip_bfloat16* gd_bf = (__hip_bfloat16*)(ws + off); off += 262144;
  if (ws_size < off * sizeof(float)) return;

  float* slabs = PT;                              // dead before chunk_mid writes PT
  __hip_bfloat16* o2b = (__hip_bfloat16*)a_full;  // a_full dead after gc_lds
  __hip_bfloat16* Wt_au = Wt_aug;
  __hip_bfloat16* Wt_gu = Wt_aug + (size_t)C_ * HD_;

  // Phase 0: bf16 conversions (4 tconv launches instead of 8)
  cvt_bf<<<(int)((size_t)M_ * D_ / 1024), 256, 0, stream>>>(x, xb);
  tconv_z<<<dim3(C_ / 32, D_ / 32, 3), 256, 0, stream>>>(Wq, Wk, Wv, Wt_qkv, D_, C_);
  tconv_z<<<dim3(HD_ / 32, D_ / 32, 2), 256, 0, stream>>>(Wad, Wgd, Wgd, Wt_dg, D_, HD_);
  tconv_z<<<dim3(C_ / 32, HD_ / 32, 2), 256, 0, stream>>>(Wau, Wgu, Wgu, Wt_aug, HD_, C_);
  tconv_z<<<dim3(D_ / 32, C_ / 32, 1), 256, 0, stream>>>(Wo, Wo, Wo, Wt_o, C_, D_);

  // Phase 1: projections (MFMA bf16)
  gemm_bf16k<__hip_bfloat16><<<dim3(3 * C_ / 128, M_ / 128), 256, 0, stream>>>(
      xb, Wt_qkv, pre_qkv, 3 * C_, D_);
  gemm_bf16_sk<<<dim3(2, M_ / 128, 4), 256, 0, stream>>>(xb, Wt_dg, slabs, 256, D_, D_ / 4);
  reduce_dg<<<(int)((size_t)M_ * 256 / 256), 256, 0, stream>>>(slabs, ad_bf, gd_bf);
  gemm_bf16k<float><<<dim3(C_ / 128, M_ / 128), 256, 0, stream>>>(ad_bf, Wt_au, a_full, C_, HD_);
  gemm_bf16k<__hip_bfloat16><<<dim3(C_ / 128, M_ / 128), 256, 0, stream>>>(
      gd_bf, Wt_gu, gatef, C_, HD_);

  // Phase 2: gate cumsum, then fused q/k/v conv
  gc_lds<<<B_ * H_ * NT_, 256, 0, stream>>>(a_full, gc_g);
  conv_qkv<<<B_ * T_ * H_, 128, 0, stream>>>(pre_qkv, gc_g, cqw, cqb, ckw, ckb,
                                             cvw, cvb, qg_bf, kp_bf, km_bf, v_bf);

  // Phase 3: fused pairdot + solve + ppre, then state scan
  chunk_mid<<<B_ * H_ * NT_, 256, 0, stream>>>(qg_bf, kp_bf, km_bf, v_bf,
                                               Aq_bf, w_bf, u_g, PT);
  scan_pt<<<B_ * H_ * HD_, 128, 0, stream>>>(PT, gc_g, STg, Sout);

  // Phase 4: fused output tail + projection
  chunk_tail<<<B_ * H_ * NT_, 256, 0, stream>>>(qg_bf, w_bf, u_g, Aq_bf, STg,
                                                gatef, normw, o2b);
  gemm_bf16k<float><<<dim3(D_ / 128, M_ / 128), 256, 0, stream>>>(o2b, Wt_o, outp, D_, C_);
}